// Round 16
// baseline (3150.373 us; speedup 1.0000x reference)
//
#include <hip/hip_runtime.h>
#include <math.h>

typedef unsigned short ushort_t;
typedef __attribute__((ext_vector_type(8))) short short8;    // 8 bf16 (4 VGPRs)
typedef __attribute__((ext_vector_type(4))) float f32x4;     // 16x16 MFMA C/D
typedef __attribute__((ext_vector_type(16))) float f32x16;   // 32x32 MFMA C/D

#define Bn 2048
#define Hn 1024
#define En 512
#define NSLOT 9

__device__ __forceinline__ float sigmoidf_(float x) { return 1.f / (1.f + expf(-x)); }

__device__ __forceinline__ ushort_t bf16rn(float f) {
  unsigned u = __float_as_uint(f);
  return (ushort_t)((u + 0x7FFFu + ((u >> 16) & 1u)) >> 16);
}

__device__ __forceinline__ float bf2f(ushort_t u) {
  return __uint_as_float(((unsigned)u) << 16);
}

__global__ __launch_bounds__(256) void cvt_bf16_kernel(const float* __restrict__ in,
                                                       ushort_t* __restrict__ out, int n4) {
  int i = blockIdx.x * 256 + threadIdx.x;
  if (i < n4) {
    float4 v = ((const float4*)in)[i];
    ushort4 o;
    o.x = bf16rn(v.x); o.y = bf16rn(v.y); o.z = bf16rn(v.z); o.w = bf16rn(v.w);
    ((ushort4*)out)[i] = o;
  }
}

// unemb_W [254][1024] f32 -> [256][1024] bf16, rows 254/255 = 0
__global__ __launch_bounds__(256) void cvt_pad_wu_kernel(const float* __restrict__ src,
                                                         ushort_t* __restrict__ dst) {
  int i = blockIdx.x * 256 + threadIdx.x;
  if (i < 256 * Hn / 4) {
    float4 v = make_float4(0.f, 0.f, 0.f, 0.f);
    if (i * 4 < 254 * Hn) v = ((const float4*)src)[i];
    ushort4 o;
    o.x = bf16rn(v.x); o.y = bf16rn(v.y); o.z = bf16rn(v.z); o.w = bf16rn(v.w);
    ((ushort4*)dst)[i] = o;
  }
}

#define GLOAD(gsrc, ldst)                                                      \
  __builtin_amdgcn_global_load_lds(                                            \
      (const __attribute__((address_space(1))) unsigned int*)(gsrc),           \
      (__attribute__((address_space(3))) unsigned int*)(ldst), 16, 0, 0)

// counted-vmcnt pipeline barrier: drain own loads to N, raw barrier, pin sched.
#define PIPE_BAR(N)                                                            \
  asm volatile("s_waitcnt vmcnt(" #N ")" ::: "memory");                        \
  __builtin_amdgcn_s_barrier();                                                \
  __builtin_amdgcn_sched_barrier(0);

// bank swizzle for 64 B rows (4 chunks): chunk' = chunk ^ ((row>>1)&3)
#define SWZ(ROW, C) ((C) ^ (((ROW) >> 1) & 3))
// bank swizzle for 128 B rows (8 chunks): chunk' = chunk ^ (row&7)
#define SWZ64(ROW, C) ((C) ^ ((ROW) & 7))

// ---------------------------------------------------------------------------
// xp table: P[v][g] = sum_e emb[v][e]*Wih[g][e] + bih[g]   (v<256, g<3072)
// ---------------------------------------------------------------------------
__global__ __launch_bounds__(256) void pgemm_kernel(
    const ushort_t* __restrict__ A,    // [256][512] bf16 (emb)
    const ushort_t* __restrict__ Bw,   // [3072][512] bf16 (Wih)
    const float* __restrict__ bias,    // [3072] (bih)
    float* __restrict__ P)             // [256][3072] f32
{
  __shared__ __align__(16) ushort_t As[64 * 32];
  __shared__ __align__(16) ushort_t Bs[64 * 32];

  const int tid = threadIdx.x;
  const int lane = tid & 63;
  const int wid = tid >> 6;
  const int wr = wid >> 1, wc = wid & 1;
  const int m0 = blockIdx.x * 64;
  const int n0 = blockIdx.y * 64;

  const int srow = tid >> 2;
  const int sseg = SWZ(srow, tid & 3) * 8;
  const ushort_t* aP = A + (size_t)(m0 + srow) * En + sseg;
  const ushort_t* bP = Bw + (size_t)(n0 + srow) * En + sseg;

  const int kc = lane >> 4;
  const int ra0 = wr * 32 + (lane & 15), ra1 = ra0 + 16;
  const int rb0 = wc * 32 + (lane & 15), rb1 = rb0 + 16;
  const int aoff0 = ra0 * 32 + SWZ(ra0, kc) * 8;
  const int aoff1 = ra1 * 32 + SWZ(ra1, kc) * 8;
  const int boff0 = rb0 * 32 + SWZ(rb0, kc) * 8;
  const int boff1 = rb1 * 32 + SWZ(rb1, kc) * 8;

  const f32x4 zero = {0.f, 0.f, 0.f, 0.f};
  f32x4 acc[2][2] = {{zero, zero}, {zero, zero}};

  for (int k0 = 0; k0 < En; k0 += 32) {
    GLOAD(aP + k0, &As[wid * 512]);
    GLOAD(bP + k0, &Bs[wid * 512]);
    asm volatile("s_waitcnt vmcnt(0)" ::: "memory");
    __syncthreads();
    short8 a0 = *(const short8*)&As[aoff0];
    short8 a1 = *(const short8*)&As[aoff1];
    short8 b0 = *(const short8*)&Bs[boff0];
    short8 b1 = *(const short8*)&Bs[boff1];
    acc[0][0] = __builtin_amdgcn_mfma_f32_16x16x32_bf16(a0, b0, acc[0][0], 0, 0, 0);
    acc[0][1] = __builtin_amdgcn_mfma_f32_16x16x32_bf16(a0, b1, acc[0][1], 0, 0, 0);
    acc[1][0] = __builtin_amdgcn_mfma_f32_16x16x32_bf16(a1, b0, acc[1][0], 0, 0, 0);
    acc[1][1] = __builtin_amdgcn_mfma_f32_16x16x32_bf16(a1, b1, acc[1][1], 0, 0, 0);
    __syncthreads();
  }

  const int colb = n0 + wc * 32 + (lane & 15);
  const int rowb = m0 + wr * 32 + ((lane >> 4) << 2);
#pragma unroll
  for (int j = 0; j < 2; ++j) {
    const int g = colb + j * 16;
    const float bv = bias[g];
#pragma unroll
    for (int i = 0; i < 2; ++i)
#pragma unroll
      for (int reg = 0; reg < 4; ++reg)
        P[(size_t)(rowb + i * 16 + reg) * 3072 + g] = acc[i][j][reg] + bv;
  }
}

// ---------------------------------------------------------------------------
// GRU step v7b: tile 64(batch) x 64(h-col) x 3 gates, 512 threads (8 waves),
// 512 blocks = 2 blocks/CU = 16 waves/CU.  MFMA 32x32x16 (2x FLOP/instr).
// Wave wid: position p=wid&3 -> (pr,pc) 32x32 sub-tile; khalf=wid>>2 owns a
// K-half of each staged BK=64 buffer. Combine via LDS scratch once per step.
// Race-free 2-phase loop (guide T3 recipe): STAGE(next) -> KSTEP(cur) ->
// vmcnt(0)+raw barrier.  All LDS through one char[] carve (no UB overlay).
// ---------------------------------------------------------------------------
#define KSTEP(BUF)                                                             \
  {                                                                            \
    _Pragma("unroll") for (int ks = 0; ks < 2; ++ks) {                         \
      short8 a  = *(const short8*)(AsG(BUF) + aoff[ks]);                       \
      short8 b0 = *(const short8*)(BsG(BUF, 0) + boff[ks]);                    \
      short8 b1 = *(const short8*)(BsG(BUF, 1) + boff[ks]);                    \
      short8 b2 = *(const short8*)(BsG(BUF, 2) + boff[ks]);                    \
      __builtin_amdgcn_s_setprio(1);                                           \
      acc0 = __builtin_amdgcn_mfma_f32_32x32x16_bf16(a, b0, acc0, 0, 0, 0);    \
      acc1 = __builtin_amdgcn_mfma_f32_32x32x16_bf16(a, b1, acc1, 0, 0, 0);    \
      acc2 = __builtin_amdgcn_mfma_f32_32x32x16_bf16(a, b2, acc2, 0, 0, 0);    \
      __builtin_amdgcn_s_setprio(0);                                           \
    }                                                                          \
  }

#define GSTAGE(BUF, T)                                                         \
  {                                                                            \
    const int k0_ = (T) * 64;                                                  \
    GLOAD(aSrc + k0_, AsG(BUF) + wid * 512);                                   \
    GLOAD(bSrc0 + k0_, BsG(BUF, 0) + wid * 512);                               \
    GLOAD(bSrc1 + k0_, BsG(BUF, 1) + wid * 512);                               \
    GLOAD(bSrc2 + k0_, BsG(BUF, 2) + wid * 512);                               \
  }

__global__ __launch_bounds__(512, 4) void gru_step_mfma(
    const int* __restrict__ seq_row,
    const float* __restrict__ P,          // [256][3072] f32 (xp + bih)
    const ushort_t* __restrict__ Whh,     // [3H][H] bf16
    const float* __restrict__ bhh,        // [3H]
    const ushort_t* __restrict__ h_in_b,  // [B][H] bf16
    ushort_t* __restrict__ h_out_b)       // [B][H] bf16
{
  // LDS carve: As[2][4096]u16 (16 KB) | Bs[2][3][4096]u16 (48 KB) | toks (256 B)
  // combine scratch (48 KB, f32) overlays [0, 48 KB) after staging is done.
  __shared__ __align__(16) char smem[16 * 1024 + 48 * 1024 + 256];
#define AsG(BUF) ((ushort_t*)smem + (BUF) * 4096)
#define BsG(BUF, G) ((ushort_t*)(smem + 16 * 1024) + ((BUF) * 3 + (G)) * 4096)
  int* toks = (int*)(smem + 64 * 1024);
  float* sc = (float*)smem;

  const int tid = threadIdx.x;
  const int lane = tid & 63;
  const int wid = tid >> 6;     // 0..7
  const int p = wid & 3;        // 32x32 position
  const int pr = p & 1, pc = p >> 1;
  const int khalf = wid >> 2;   // K-half of each BK=64 stage
  const int kg = lane >> 5;     // frag k-group (0/1)

  // XCD-affine swizzle: XCD q owns n-tiles {2q, 2q+1}. 512 blocks = 2/CU.
  const int bid = blockIdx.x;
  const int q = bid & 7, t_ = bid >> 3;          // t_ in 0..63
  const int n0 = ((q << 1) | (t_ & 1)) * 64;
  const int m0 = (t_ >> 1) * 64;                 // 32 m-tiles

  if (tid < 64) toks[tid] = seq_row[m0 + tid];
  __syncthreads();

  // staging: thread -> (row tid>>3, chunk tid&7); dest linear, source
  // chunk inverse-swizzled (SWZ64 involution). 4 loads/thread/stage.
  const int srow = tid >> 3;                     // 0..63
  const int sseg = SWZ64(srow, tid & 7) * 8;     // ushort offset in 64-elem row

  const ushort_t* aSrc  = h_in_b + (size_t)(m0 + srow) * Hn + sseg;
  const ushort_t* bSrc0 = Whh + (size_t)(0 * Hn + n0 + srow) * Hn + sseg;
  const ushort_t* bSrc1 = Whh + (size_t)(1 * Hn + n0 + srow) * Hn + sseg;
  const ushort_t* bSrc2 = Whh + (size_t)(2 * Hn + n0 + srow) * Hn + sseg;

  // 32x32x16 fragment offsets: row = band*32 + (lane&31), k-chunk =
  // khalf*4 + ks*2 + kg; LDS slot inverse-swizzled (involution).
  const int arow = pr * 32 + (lane & 31);
  const int brow = pc * 32 + (lane & 31);
  int aoff[2], boff[2];
#pragma unroll
  for (int ks = 0; ks < 2; ++ks) {
    const int c = khalf * 4 + ks * 2 + kg;       // chunk 0..7
    aoff[ks] = arow * 64 + SWZ64(arow, c) * 8;
    boff[ks] = brow * 64 + SWZ64(brow, c) * 8;
  }

  f32x16 acc0, acc1, acc2;
#pragma unroll
  for (int r = 0; r < 16; ++r) { acc0[r] = 0.f; acc1[r] = 0.f; acc2[r] = 0.f; }

  // ---- race-free 2-phase K-loop (guide T3 recipe): 16 BK=64 steps ----
  GSTAGE(0, 0);
  PIPE_BAR(0)                 // prologue: buffer 0 resident
  int buf = 0;
  for (int t = 0; t < 15; ++t) {
    GSTAGE(buf ^ 1, t + 1);   // issue next stage (flies under KSTEP)
    KSTEP(buf)
    PIPE_BAR(0)               // drain + barrier: next buffer ready, reads done
    buf ^= 1;
  }
  KSTEP(buf)

  // ---- K-split combine via LDS scratch (48 KB, staging region reuse) ----
  __syncthreads();            // all staging reads done; safe to overwrite
  if (khalf == 1) {
#pragma unroll
    for (int g = 0; g < 3; ++g) {
#pragma unroll
      for (int rq = 0; rq < 4; ++rq) {
        const f32x16 A = (g == 0) ? acc0 : (g == 1) ? acc1 : acc2;
        f32x4 v = {A[rq * 4 + 0], A[rq * 4 + 1], A[rq * 4 + 2], A[rq * 4 + 3]};
        *(f32x4*)&sc[(((p * 3 + g) * 4 + rq) * 64 + lane) * 4] = v;
      }
    }
  }
  __syncthreads();
  if (khalf == 0) {
#pragma unroll
    for (int g = 0; g < 3; ++g) {
#pragma unroll
      for (int rq = 0; rq < 4; ++rq) {
        const f32x4 v = *(const f32x4*)&sc[(((p * 3 + g) * 4 + rq) * 64 + lane) * 4];
#pragma unroll
        for (int j = 0; j < 4; ++j) {
          if (g == 0) acc0[rq * 4 + j] += v[j];
          else if (g == 1) acc1[rq * 4 + j] += v[j];
          else acc2[rq * 4 + j] += v[j];
        }
      }
    }

    // ---- epilogue: xp gather from P + gates + state update (bf16 h) ----
    // C/D 32x32: col = lane&31, row = (reg&3) + 8*(reg>>2) + 4*(lane>>5)
    const int n = n0 + pc * 32 + (lane & 31);
    const float bhr = bhh[n];
    const float bhz = bhh[Hn + n];
    const float bhn = bhh[2 * Hn + n];
#pragma unroll
    for (int r = 0; r < 16; ++r) {
      const int lr = pr * 32 + (r & 3) + 8 * (r >> 2) + 4 * kg;
      const int m = m0 + lr;
      const float* prow = P + (size_t)toks[lr] * 3072;
      const float xr = prow[n];
      const float xz = prow[Hn + n];
      const float xn = prow[2 * Hn + n];
      const float rg = sigmoidf_(xr + acc0[r] + bhr);
      const float zg = sigmoidf_(xz + acc1[r] + bhz);
      const float ng = tanhf(xn + rg * (acc2[r] + bhn));
      const float hv = bf2f(h_in_b[(size_t)m * Hn + n]);  // L2-hot re-read
      h_out_b[(size_t)m * Hn + n] = bf16rn((1.f - zg) * ng + zg * hv);
    }
  }
}

// ---------------------------------------------------------------------------
// Batched unembed + log-softmax + NLL. Block = 64 rows x 256 cols, K=1024
// (4x4 frags, 16 MFMA/iter, uniform 5 loads/wave/iter). 32 blocks per step.
// ---------------------------------------------------------------------------
#define USTAGE(BUF, T)                                                         \
  {                                                                            \
    const int k0_ = (T) * 32;                                                  \
    GLOAD(ha + k0_, AsU(BUF) + uwid * 512);                                    \
    GLOAD(w0 + k0_, BsU(BUF) + 0 * 2048 + uwid * 512);                         \
    GLOAD(w1 + k0_, BsU(BUF) + 1 * 2048 + uwid * 512);                         \
    GLOAD(w2 + k0_, BsU(BUF) + 2 * 2048 + uwid * 512);                         \
    GLOAD(w3 + k0_, BsU(BUF) + 3 * 2048 + uwid * 512);                         \
  }

#define UKSTEP(BUF)                                                            \
  {                                                                            \
    short8 a_[4], b_[4];                                                       \
    _Pragma("unroll") for (int fi = 0; fi < 4; ++fi)                           \
        a_[fi] = *(const short8*)(AsU(BUF) + uaoff[fi]);                       \
    _Pragma("unroll") for (int fj = 0; fj < 4; ++fj)                           \
        b_[fj] = *(const short8*)(BsU(BUF) + uboff[fj]);                       \
    _Pragma("unroll") for (int fi = 0; fi < 4; ++fi)                           \
        _Pragma("unroll") for (int fj = 0; fj < 4; ++fj)                       \
            acc[fi][fj] = __builtin_amdgcn_mfma_f32_16x16x32_bf16(             \
                a_[fi], b_[fj], acc[fi][fj], 0, 0, 0);                         \
  }

__global__ __launch_bounds__(256) void unembed_batched(
    const ushort_t* __restrict__ hseq,  // [NSLOT][B][H] bf16 ring
    int s0,
    const ushort_t* __restrict__ Wp,    // [256][H] bf16 (rows 254/255 = 0)
    const float* __restrict__ bu,       // [254]
    const int* __restrict__ tgt_seq,    // [S_tgt][B]
    double* __restrict__ loss_acc,
    unsigned long long* __restrict__ cnt_acc)
{
  __shared__ __align__(16) char usmem[16 * 1024 + 64 * 1024];  // 80 KB
#define AsU(BUF) ((ushort_t*)usmem + (BUF) * 2048)             // 4 x 4 KB
#define BsU(BUF) ((ushort_t*)(usmem + 16 * 1024) + (BUF) * 8192)  // 4 x 16 KB
  float* lg = (float*)usmem;                                   // [64][256] overlay

  const int tid = threadIdx.x;
  const int lane = tid & 63;
  const int uwid = tid >> 6;

  const int step = blockIdx.x >> 5;                 // 32 blocks per step
  const int slot = (s0 + step) % NSLOT;
  const int m0 = (blockIdx.x & 31) * 64;
  const ushort_t* h_b = hseq + (size_t)slot * Bn * Hn;
  const int* labels = tgt_seq + (size_t)(s0 + step + 1) * Bn;

  const int srow = tid >> 2;
  const int sseg = SWZ(srow, tid & 3) * 8;

  const ushort_t* ha = h_b + (size_t)(m0 + srow) * Hn + sseg;
  const ushort_t* w0 = Wp + (size_t)(0 * 64 + srow) * Hn + sseg;
  const ushort_t* w1 = Wp + (size_t)(1 * 64 + srow) * Hn + sseg;
  const ushort_t* w2 = Wp + (size_t)(2 * 64 + srow) * Hn + sseg;
  const ushort_t* w3 = Wp + (size_t)(3 * 64 + srow) * Hn + sseg;

  const int kc = lane >> 4;
  int uaoff[4], uboff[4];
#pragma unroll
  for (int fi = 0; fi < 4; ++fi) {
    const int ra = fi * 16 + (lane & 15);
    uaoff[fi] = ra * 32 + SWZ(ra, kc) * 8;
  }
#pragma unroll
  for (int fj = 0; fj < 4; ++fj) {
    const int rb = uwid * 64 + fj * 16 + (lane & 15);
    uboff[fj] = rb * 32 + SWZ(rb, kc) * 8;
  }

  const f32x4 zero = {0.f, 0.f, 0.f, 0.f};
  f32x4 acc[4][4];
#pragma unroll
  for (int fi = 0; fi < 4; ++fi)
#pragma unroll
    for (int fj = 0; fj < 4; ++fj) acc[fi][fj] = zero;

  USTAGE(0, 0);
  USTAGE(1, 1);
  USTAGE(2, 2);
  for (int t = 0; t < 29; ++t) {
    PIPE_BAR(10)
    USTAGE((t + 3) & 3, t + 3);
    UKSTEP(t & 3)
  }
  PIPE_BAR(10)  // t=29
  UKSTEP(1)
  PIPE_BAR(5)   // t=30
  UKSTEP(2)
  PIPE_BAR(0)   // t=31
  UKSTEP(3)

  // ---- logits -> LDS overlay (bias + mask pad cols) ----
  __syncthreads();  // all ds_reads of staging done; safe to overwrite with lg
#pragma unroll
  for (int fj = 0; fj < 4; ++fj) {
    const int col = uwid * 64 + fj * 16 + (lane & 15);
    const float bv = (col < 254) ? bu[col] : 0.f;
#pragma unroll
    for (int fi = 0; fi < 4; ++fi) {
#pragma unroll
      for (int reg = 0; reg < 4; ++reg) {
        const int row = fi * 16 + (lane >> 4) * 4 + reg;
        lg[row * 256 + col] = (col < 254) ? (acc[fi][fj][reg] + bv) : -1e30f;
      }
    }
  }
  __syncthreads();

  // ---- per-row log-softmax + NLL: wave w handles rows [w*16, w*16+16) ----
  float wsum = 0.f;
  int wcnt = 0;
#pragma unroll
  for (int rr = 0; rr < 16; ++rr) {
    const int r = uwid * 16 + rr;
    const float4 v4 = *(const float4*)&lg[r * 256 + lane * 4];
    float mx = fmaxf(fmaxf(v4.x, v4.y), fmaxf(v4.z, v4.w));
    for (int o = 32; o > 0; o >>= 1) mx = fmaxf(mx, __shfl_xor(mx, o));
    float s = expf(v4.x - mx) + expf(v4.y - mx) + expf(v4.z - mx) + expf(v4.w - mx);
    for (int o = 32; o > 0; o >>= 1) s += __shfl_xor(s, o);
    if (lane == 0) {
      const int lab = labels[m0 + r];
      if (lab != 0) {
        wsum += (logf(s) + mx) - lg[r * 256 + lab - 2];
        wcnt += 1;
      }
    }
  }
  if (lane == 0) {
    atomicAdd(loss_acc, (double)wsum);
    atomicAdd(cnt_acc, (unsigned long long)wcnt);
  }
}

__global__ void finalize_kernel(const double* __restrict__ loss_acc,
                                const unsigned long long* __restrict__ cnt_acc,
                                unsigned* __restrict__ out)
{
  unsigned long long cnt = cnt_acc[0];
  if (cnt == 0ull) cnt = 1ull;
  const float f = (float)(loss_acc[0] / (double)cnt);
  const unsigned u = __float_as_uint(f);
  const unsigned bf = (u + 0x7FFFu + ((u >> 16) & 1u)) >> 16;
  out[0] = (u & 0xFFFF0000u) | (bf & 0xFFFFu);
}

extern "C" void kernel_launch(void* const* d_in, const int* in_sizes, int n_in,
                              void* d_out, int out_size, void* d_ws, size_t ws_size,
                              hipStream_t stream)
{
  const int* src_seq = (const int*)d_in[0];
  const int* tgt_seq = (const int*)d_in[1];
  const float* enc_emb = (const float*)d_in[2];
  const float* enc_Wih = (const float*)d_in[3];
  const float* enc_Whh = (const float*)d_in[4];
  const float* enc_bih = (const float*)d_in[5];
  const float* enc_bhh = (const float*)d_in[6];
  const float* dec_emb = (const float*)d_in[7];
  const float* dec_Wih = (const float*)d_in[8];
  const float* dec_Whh = (const float*)d_in[9];
  const float* dec_bih = (const float*)d_in[10];
  const float* dec_bhh = (const float*)d_in[11];
  const float* unemb_W = (const float*)d_in[12];
  const float* unemb_b = (const float*)d_in[13];

  // ---- workspace carve-up (~64 MB) ----
  char* p = (char*)d_ws;
  ushort_t* hseq = (ushort_t*)p; p += (size_t)NSLOT * Bn * Hn * 2;   // 36 MB ring
  ushort_t* eWih = (ushort_t*)p; p += (size_t)3 * Hn * En * 2;
  ushort_t* eWhh = (ushort_t*)p; p += (size_t)3 * Hn * Hn * 2;
  ushort_t* dWih = (ushort_t*)p; p += (size_t)3 * Hn * En * 2;
  ushort_t* dWhh = (ushort_t*)p; p += (size_t)3 * Hn * Hn * 2;
  ushort_t* eEmb = (ushort_t*)p; p += (size_t)256 * En * 2;
  ushort_t* dEmb = (ushort_t*)p; p += (size_t)256 * En * 2;
  ushort_t* Wp   = (ushort_t*)p; p += (size_t)256 * Hn * 2;
  float* Pe = (float*)p; p += (size_t)256 * 3072 * 4;   // 3 MB
  float* Pd = (float*)p; p += (size_t)256 * 3072 * 4;   // 3 MB
  double* loss_acc = (double*)p;
  unsigned long long* cnt_acc = (unsigned long long*)(p + 8);

  ushort_t* slot7 = hseq + (size_t)7 * Bn * Hn;
  ushort_t* slot8 = hseq + (size_t)8 * Bn * Hn;

  hipMemsetAsync(slot7, 0, (size_t)Bn * Hn * 2, stream);
  hipMemsetAsync(loss_acc, 0, 16, stream);

  // ---- fp32 -> bf16 conversions ----
  struct { const float* src; ushort_t* dst; int n; } cv[6] = {
      {enc_Wih, eWih, 3 * Hn * En}, {enc_Whh, eWhh, 3 * Hn * Hn},
      {dec_Wih, dWih, 3 * Hn * En}, {dec_Whh, dWhh, 3 * Hn * Hn},
      {enc_emb, eEmb, 256 * En},    {dec_emb, dEmb, 256 * En}};
  for (int i = 0; i < 6; ++i) {
    int n4 = cv[i].n / 4;
    cvt_bf16_kernel<<<(n4 + 255) / 256, 256, 0, stream>>>(cv[i].src, cv[i].dst, n4);
  }
  cvt_pad_wu_kernel<<<(256 * Hn / 4 + 255) / 256, 256, 0, stream>>>(unemb_W, Wp);

  // ---- xp tables: P = emb @ Wih^T + bih ----
  {
    const dim3 pg(4, 48);
    pgemm_kernel<<<pg, 256, 0, stream>>>(eEmb, eWih, enc_bih, Pe);
    pgemm_kernel<<<pg, 256, 0, stream>>>(dEmb, dWih, dec_bih, Pd);
  }

  // ---- encoder: 64 steps, ping-pong slots 7/8 (bf16 h only) ----
  const ushort_t* in_b = slot7;
  for (int s = 0; s < 64; ++s) {
    ushort_t* out_b = (s & 1) ? slot7 : slot8;
    gru_step_mfma<<<512, 512, 0, stream>>>(src_seq + (size_t)s * Bn, Pe, eWhh, enc_bhh,
                                           in_b, out_b);
    in_b = out_b;
  }
  // encoder final: slot7 (s=63 odd)

  // ---- decoder: 47 steps; h_b history ring; batched unembed every 8 ----
  int done = 0;
  for (int s = 0; s < 47; ++s) {
    const ushort_t* din_b = (s == 0) ? slot7 : hseq + (size_t)((s - 1) % NSLOT) * Bn * Hn;
    ushort_t* dout_b = hseq + (size_t)(s % NSLOT) * Bn * Hn;
    gru_step_mfma<<<512, 512, 0, stream>>>(tgt_seq + (size_t)s * Bn, Pd, dWhh, dec_bhh,
                                           din_b, dout_b);
    if (s == 7 || s == 15 || s == 23 || s == 31 || s == 39 || s == 46) {
      const int cnt = s + 1 - done;
      unembed_batched<<<cnt * 32, 256, 0, stream>>>(hseq, done, Wp, unemb_b, tgt_seq,
                                                    loss_acc, cnt_acc);
      done = s + 1;
    }
  }

  finalize_kernel<<<1, 1, 0, stream>>>(loss_acc, cnt_acc, (unsigned*)d_out);
}

// Round 17
// 2592.674 us; speedup vs baseline: 1.2151x; 1.2151x over previous
//
#include <hip/hip_runtime.h>
#include <math.h>

typedef unsigned short ushort_t;
typedef __attribute__((ext_vector_type(8))) short short8;   // 8 bf16 (4 VGPRs)
typedef __attribute__((ext_vector_type(4))) float f32x4;    // MFMA C/D

#define Bn 2048
#define Hn 1024
#define En 512
#define NSLOT 9

__device__ __forceinline__ float sigmoidf_(float x) { return 1.f / (1.f + expf(-x)); }

__device__ __forceinline__ ushort_t bf16rn(float f) {
  unsigned u = __float_as_uint(f);
  return (ushort_t)((u + 0x7FFFu + ((u >> 16) & 1u)) >> 16);
}

__device__ __forceinline__ float bf2f(ushort_t u) {
  return __uint_as_float(((unsigned)u) << 16);
}

__global__ __launch_bounds__(256) void cvt_bf16_kernel(const float* __restrict__ in,
                                                       ushort_t* __restrict__ out, int n4) {
  int i = blockIdx.x * 256 + threadIdx.x;
  if (i < n4) {
    float4 v = ((const float4*)in)[i];
    ushort4 o;
    o.x = bf16rn(v.x); o.y = bf16rn(v.y); o.z = bf16rn(v.z); o.w = bf16rn(v.w);
    ((ushort4*)out)[i] = o;
  }
}

// unemb_W [254][1024] f32 -> [256][1024] bf16, rows 254/255 = 0
__global__ __launch_bounds__(256) void cvt_pad_wu_kernel(const float* __restrict__ src,
                                                         ushort_t* __restrict__ dst) {
  int i = blockIdx.x * 256 + threadIdx.x;
  if (i < 256 * Hn / 4) {
    float4 v = make_float4(0.f, 0.f, 0.f, 0.f);
    if (i * 4 < 254 * Hn) v = ((const float4*)src)[i];
    ushort4 o;
    o.x = bf16rn(v.x); o.y = bf16rn(v.y); o.z = bf16rn(v.z); o.w = bf16rn(v.w);
    ((ushort4*)dst)[i] = o;
  }
}

#define GLOAD(gsrc, ldst)                                                      \
  __builtin_amdgcn_global_load_lds(                                            \
      (const __attribute__((address_space(1))) unsigned int*)(gsrc),           \
      (__attribute__((address_space(3))) unsigned int*)(ldst), 16, 0, 0)

// counted-vmcnt pipeline barrier: drain own loads to N, raw barrier, pin sched.
#define PIPE_BAR(N)                                                            \
  asm volatile("s_waitcnt vmcnt(" #N ")" ::: "memory");                        \
  __builtin_amdgcn_s_barrier();                                                \
  __builtin_amdgcn_sched_barrier(0);

// bank swizzle for 64 B rows (4 chunks): chunk' = chunk ^ ((row>>1)&3)
#define SWZ(ROW, C) ((C) ^ (((ROW) >> 1) & 3))
// bank swizzle for 128 B rows (8 chunks): chunk' = chunk ^ (row&7)
#define SWZ64(ROW, C) ((C) ^ ((ROW) & 7))

// ---------------------------------------------------------------------------
// xp table: P[v][g] = sum_e emb[v][e]*Wih[g][e] + bih[g]   (v<256, g<3072)
// ---------------------------------------------------------------------------
__global__ __launch_bounds__(256) void pgemm_kernel(
    const ushort_t* __restrict__ A,    // [256][512] bf16 (emb)
    const ushort_t* __restrict__ Bw,   // [3072][512] bf16 (Wih)
    const float* __restrict__ bias,    // [3072] (bih)
    float* __restrict__ P)             // [256][3072] f32
{
  __shared__ __align__(16) ushort_t As[64 * 32];
  __shared__ __align__(16) ushort_t Bs[64 * 32];

  const int tid = threadIdx.x;
  const int lane = tid & 63;
  const int wid = tid >> 6;
  const int wr = wid >> 1, wc = wid & 1;
  const int m0 = blockIdx.x * 64;
  const int n0 = blockIdx.y * 64;

  const int srow = tid >> 2;
  const int sseg = SWZ(srow, tid & 3) * 8;
  const ushort_t* aP = A + (size_t)(m0 + srow) * En + sseg;
  const ushort_t* bP = Bw + (size_t)(n0 + srow) * En + sseg;

  const int kc = lane >> 4;
  const int ra0 = wr * 32 + (lane & 15), ra1 = ra0 + 16;
  const int rb0 = wc * 32 + (lane & 15), rb1 = rb0 + 16;
  const int aoff0 = ra0 * 32 + SWZ(ra0, kc) * 8;
  const int aoff1 = ra1 * 32 + SWZ(ra1, kc) * 8;
  const int boff0 = rb0 * 32 + SWZ(rb0, kc) * 8;
  const int boff1 = rb1 * 32 + SWZ(rb1, kc) * 8;

  const f32x4 zero = {0.f, 0.f, 0.f, 0.f};
  f32x4 acc[2][2] = {{zero, zero}, {zero, zero}};

  for (int k0 = 0; k0 < En; k0 += 32) {
    GLOAD(aP + k0, &As[wid * 512]);
    GLOAD(bP + k0, &Bs[wid * 512]);
    asm volatile("s_waitcnt vmcnt(0)" ::: "memory");
    __syncthreads();
    short8 a0 = *(const short8*)&As[aoff0];
    short8 a1 = *(const short8*)&As[aoff1];
    short8 b0 = *(const short8*)&Bs[boff0];
    short8 b1 = *(const short8*)&Bs[boff1];
    acc[0][0] = __builtin_amdgcn_mfma_f32_16x16x32_bf16(a0, b0, acc[0][0], 0, 0, 0);
    acc[0][1] = __builtin_amdgcn_mfma_f32_16x16x32_bf16(a0, b1, acc[0][1], 0, 0, 0);
    acc[1][0] = __builtin_amdgcn_mfma_f32_16x16x32_bf16(a1, b0, acc[1][0], 0, 0, 0);
    acc[1][1] = __builtin_amdgcn_mfma_f32_16x16x32_bf16(a1, b1, acc[1][1], 0, 0, 0);
    __syncthreads();
  }

  const int colb = n0 + wc * 32 + (lane & 15);
  const int rowb = m0 + wr * 32 + ((lane >> 4) << 2);
#pragma unroll
  for (int j = 0; j < 2; ++j) {
    const int g = colb + j * 16;
    const float bv = bias[g];
#pragma unroll
    for (int i = 0; i < 2; ++i)
#pragma unroll
      for (int reg = 0; reg < 4; ++reg)
        P[(size_t)(rowb + i * 16 + reg) * 3072 + g] = acc[i][j][reg] + bv;
  }
}

// ---------------------------------------------------------------------------
// GRU step v6 (R13 known-good): tile 64(batch) x 64(h-col) x 3 gates,
// 512 threads (8 waves), 512 blocks => 2 blocks/CU, 16 waves/CU.
// BK=64, 16 K-iters, 2 LDS buffers, 2-phase counted pipeline:
// issue stage t+1 -> vmcnt(4) (drain t, keep t+1 in flight) -> barrier -> MFMA.
// Wave wid: rows (wid&1)*32..+32, cols (wid>>1)*16..+16, all 3 gates.
// ---------------------------------------------------------------------------
#define KSTEP(BUF)                                                             \
  {                                                                            \
    short8 aF[2][2], bF[3][2];                                                 \
    _Pragma("unroll") for (int fi = 0; fi < 2; ++fi)                           \
        _Pragma("unroll") for (int h = 0; h < 2; ++h)                          \
            aF[fi][h] = *(const short8*)&As[BUF][aoff[fi][h]];                 \
    _Pragma("unroll") for (int g = 0; g < 3; ++g)                              \
        _Pragma("unroll") for (int h = 0; h < 2; ++h)                          \
            bF[g][h] = *(const short8*)&Bs[BUF][g][boff[h]];                   \
    __builtin_amdgcn_s_setprio(1);                                             \
    _Pragma("unroll") for (int h = 0; h < 2; ++h)                              \
        _Pragma("unroll") for (int g = 0; g < 3; ++g)                          \
            _Pragma("unroll") for (int fi = 0; fi < 2; ++fi)                   \
                acc[g][fi] = __builtin_amdgcn_mfma_f32_16x16x32_bf16(          \
                    aF[fi][h], bF[g][h], acc[g][fi], 0, 0, 0);                 \
    __builtin_amdgcn_s_setprio(0);                                             \
  }

#define GSTAGE(BUF, T)                                                         \
  {                                                                            \
    const int k0_ = (T) * 64;                                                  \
    GLOAD(aSrc + k0_, &As[BUF][wid * 512]);                                    \
    GLOAD(bSrc0 + k0_, &Bs[BUF][0][wid * 512]);                                \
    GLOAD(bSrc1 + k0_, &Bs[BUF][1][wid * 512]);                                \
    GLOAD(bSrc2 + k0_, &Bs[BUF][2][wid * 512]);                                \
  }

__global__ __launch_bounds__(512, 4) void gru_step_mfma(
    const int* __restrict__ seq_row,
    const float* __restrict__ P,          // [256][3072] f32 (xp + bih)
    const ushort_t* __restrict__ Whh,     // [3H][H] bf16
    const float* __restrict__ bhh,        // [3H]
    const ushort_t* __restrict__ h_in_b,  // [B][H] bf16
    ushort_t* __restrict__ h_out_b)       // [B][H] bf16
{
  __shared__ __align__(16) ushort_t As[2][64 * 64];      // 2 x 8 KB
  __shared__ __align__(16) ushort_t Bs[2][3][64 * 64];   // 2 x 24 KB
  __shared__ int toks[64];

  const int tid = threadIdx.x;
  const int lane = tid & 63;
  const int wid = tid >> 6;     // 0..7
  const int wr = wid & 1;       // 32-row band
  const int wc = wid >> 1;      // 16-col band (0..3)

  // XCD-affine swizzle: XCD q owns n-tiles {2q, 2q+1}. 512 blocks = 2/CU.
  const int bid = blockIdx.x;
  const int q = bid & 7, t_ = bid >> 3;          // t_ in 0..63
  const int n0 = ((q << 1) | (t_ & 1)) * 64;
  const int m0 = (t_ >> 1) * 64;                 // 32 m-tiles

  if (tid < 64) toks[tid] = seq_row[m0 + tid];
  __syncthreads();

  // staging: thread -> (row tid>>3, chunk tid&7); dest linear, source
  // chunk inverse-swizzled (SWZ64 involution). 4 loads/thread/stage.
  const int srow = tid >> 3;                     // 0..63
  const int sseg = SWZ64(srow, tid & 7) * 8;     // ushort offset in 64-elem row

  const ushort_t* aSrc  = h_in_b + (size_t)(m0 + srow) * Hn + sseg;
  const ushort_t* bSrc0 = Whh + (size_t)(0 * Hn + n0 + srow) * Hn + sseg;
  const ushort_t* bSrc1 = Whh + (size_t)(1 * Hn + n0 + srow) * Hn + sseg;
  const ushort_t* bSrc2 = Whh + (size_t)(2 * Hn + n0 + srow) * Hn + sseg;

  // swizzled fragment read offsets: row*64 + (sg ^ (row&7))*8, sg = h*4 + kc
  const int kc = lane >> 4;
  int aoff[2][2], boff[2];
#pragma unroll
  for (int fi = 0; fi < 2; ++fi) {
    const int ra = wr * 32 + fi * 16 + (lane & 15);
#pragma unroll
    for (int h = 0; h < 2; ++h) aoff[fi][h] = ra * 64 + SWZ64(ra, h * 4 + kc) * 8;
  }
  {
    const int rb = wc * 16 + (lane & 15);
#pragma unroll
    for (int h = 0; h < 2; ++h) boff[h] = rb * 64 + SWZ64(rb, h * 4 + kc) * 8;
  }

  const f32x4 zero = {0.f, 0.f, 0.f, 0.f};
  f32x4 acc[3][2];
#pragma unroll
  for (int g = 0; g < 3; ++g)
#pragma unroll
    for (int fi = 0; fi < 2; ++fi) acc[g][fi] = zero;

  // ---- 2-phase counted K-loop: 16 BK=64 steps over K=1024 ----
  GSTAGE(0, 0);
  int buf = 0;
  for (int t = 0; t < 15; ++t) {
    GSTAGE(buf ^ 1, t + 1);   // next stage in flight across the barrier
    PIPE_BAR(4)               // drain stage t only
    KSTEP(buf)
    buf ^= 1;
  }
  PIPE_BAR(0)                 // t=15
  KSTEP(buf)

  // ---- epilogue: xp gather from P + gates + state update (bf16 h only) ----
  const int n = n0 + wc * 16 + (lane & 15);
  const int rowl = wr * 32 + ((lane >> 4) << 2);   // local row base
  const float bhr = bhh[n];
  const float bhz = bhh[Hn + n];
  const float bhn = bhh[2 * Hn + n];
#pragma unroll
  for (int fi = 0; fi < 2; ++fi) {
#pragma unroll
    for (int reg = 0; reg < 4; ++reg) {
      const int lr = rowl + fi * 16 + reg;
      const int m = m0 + lr;
      const float* prow = P + (size_t)toks[lr] * 3072;
      const float xr = prow[n];
      const float xz = prow[Hn + n];
      const float xn = prow[2 * Hn + n];
      const float r = sigmoidf_(xr + acc[0][fi][reg] + bhr);
      const float z = sigmoidf_(xz + acc[1][fi][reg] + bhz);
      const float nn = tanhf(xn + r * (acc[2][fi][reg] + bhn));
      const float hv = bf2f(h_in_b[(size_t)m * Hn + n]);  // L2-hot re-read
      const float o = (1.f - z) * nn + z * hv;
      h_out_b[(size_t)m * Hn + n] = bf16rn(o);
    }
  }
}

// ---------------------------------------------------------------------------
// Batched unembed v3: block = 32 rows x 256 cols, K=1024, BK=32, 2 buffers,
// 36 KB LDS -> 4 blocks/CU = 16 waves/CU (the TLP fix). 64 blocks per step.
// Waves 0-1 issue 5 loads/stage (incl. A), waves 2-3 issue 4 -> counted
// per-wave vmcnt. Logits overlay (32 KB) reuses the staging region.
// ---------------------------------------------------------------------------
#define USTAGE(BUF, T)                                                         \
  {                                                                            \
    const int k0_ = (T) * 32;                                                  \
    if (uwid < 2) GLOAD(ha + k0_, AsU(BUF) + (tid >> 2) * 32);                 \
    GLOAD(w0 + k0_, BsU(BUF) + 0 * 2048 + uwid * 512);                         \
    GLOAD(w1 + k0_, BsU(BUF) + 1 * 2048 + uwid * 512);                         \
    GLOAD(w2 + k0_, BsU(BUF) + 2 * 2048 + uwid * 512);                         \
    GLOAD(w3 + k0_, BsU(BUF) + 3 * 2048 + uwid * 512);                         \
  }

#define UPIPE_BAR(N01, N23)                                                    \
  {                                                                            \
    if (uwid < 2) { asm volatile("s_waitcnt vmcnt(" #N01 ")" ::: "memory"); }  \
    else          { asm volatile("s_waitcnt vmcnt(" #N23 ")" ::: "memory"); }  \
    __builtin_amdgcn_s_barrier();                                              \
    __builtin_amdgcn_sched_barrier(0);                                         \
  }

#define UKSTEP(BUF)                                                            \
  {                                                                            \
    short8 a_[2], b_[4];                                                       \
    _Pragma("unroll") for (int fi = 0; fi < 2; ++fi)                           \
        a_[fi] = *(const short8*)(AsU(BUF) + uaoff[fi]);                       \
    _Pragma("unroll") for (int fj = 0; fj < 4; ++fj)                           \
        b_[fj] = *(const short8*)(BsU(BUF) + uboff[fj]);                       \
    _Pragma("unroll") for (int fi = 0; fi < 2; ++fi)                           \
        _Pragma("unroll") for (int fj = 0; fj < 4; ++fj)                       \
            acc[fi][fj] = __builtin_amdgcn_mfma_f32_16x16x32_bf16(             \
                a_[fi], b_[fj], acc[fi][fj], 0, 0, 0);                         \
  }

__global__ __launch_bounds__(256) void unembed_batched(
    const ushort_t* __restrict__ hseq,  // [NSLOT][B][H] bf16 ring
    int s0,
    const ushort_t* __restrict__ Wp,    // [256][H] bf16 (rows 254/255 = 0)
    const float* __restrict__ bu,       // [254]
    const int* __restrict__ tgt_seq,    // [S_tgt][B]
    double* __restrict__ loss_acc,
    unsigned long long* __restrict__ cnt_acc)
{
  // carve: A bufs 2 x 2 KB | B bufs 2 x 16 KB  (36 KB total)
  __shared__ __align__(16) char usmem[36 * 1024];
#define AsU(BUF) ((ushort_t*)usmem + (BUF) * 1024)                 // 2 x 2 KB
#define BsU(BUF) ((ushort_t*)(usmem + 4 * 1024) + (BUF) * 8192)    // 2 x 16 KB
  float* lg = (float*)usmem;  // [32][256] f32 = 32 KB overlay (post-staging)

  const int tid = threadIdx.x;
  const int lane = tid & 63;
  const int uwid = tid >> 6;

  const int step = blockIdx.x >> 6;                 // 64 blocks per step
  const int slot = (s0 + step) % NSLOT;
  const int m0 = (blockIdx.x & 63) * 32;
  const ushort_t* h_b = hseq + (size_t)slot * Bn * Hn;
  const int* labels = tgt_seq + (size_t)(s0 + step + 1) * Bn;

  const int srow = tid >> 2;                 // 0..63 (A uses 0..31 via uwid<2)
  const int sseg = SWZ(srow, tid & 3) * 8;

  const ushort_t* ha = h_b + (size_t)(m0 + srow) * Hn + sseg;  // waves 0/1 only
  const ushort_t* w0 = Wp + (size_t)(0 * 64 + srow) * Hn + sseg;
  const ushort_t* w1 = Wp + (size_t)(1 * 64 + srow) * Hn + sseg;
  const ushort_t* w2 = Wp + (size_t)(2 * 64 + srow) * Hn + sseg;
  const ushort_t* w3 = Wp + (size_t)(3 * 64 + srow) * Hn + sseg;

  const int kc = lane >> 4;
  int uaoff[2], uboff[4];
#pragma unroll
  for (int fi = 0; fi < 2; ++fi) {
    const int ra = fi * 16 + (lane & 15);
    uaoff[fi] = ra * 32 + SWZ(ra, kc) * 8;
  }
#pragma unroll
  for (int fj = 0; fj < 4; ++fj) {
    const int rb = uwid * 64 + fj * 16 + (lane & 15);
    uboff[fj] = rb * 32 + SWZ(rb, kc) * 8;
  }

  const f32x4 zero = {0.f, 0.f, 0.f, 0.f};
  f32x4 acc[2][4];
#pragma unroll
  for (int fi = 0; fi < 2; ++fi)
#pragma unroll
    for (int fj = 0; fj < 4; ++fj) acc[fi][fj] = zero;

  // ---- 2-phase counted K-loop: 32 BK=32 steps over K=1024 ----
  USTAGE(0, 0);
  int buf = 0;
  for (int t = 0; t < 31; ++t) {
    USTAGE(buf ^ 1, t + 1);   // next stage in flight across the barrier
    UPIPE_BAR(5, 4)           // drain stage t only
    UKSTEP(buf)
    buf ^= 1;
  }
  UPIPE_BAR(0, 0)             // t=31
  UKSTEP(buf)

  // ---- logits -> LDS overlay (bias + mask pad cols) ----
  __syncthreads();  // all ds_reads of staging done; safe to overwrite with lg
#pragma unroll
  for (int fj = 0; fj < 4; ++fj) {
    const int col = uwid * 64 + fj * 16 + (lane & 15);
    const float bv = (col < 254) ? bu[col] : 0.f;
#pragma unroll
    for (int fi = 0; fi < 2; ++fi) {
#pragma unroll
      for (int reg = 0; reg < 4; ++reg) {
        const int row = fi * 16 + (lane >> 4) * 4 + reg;
        lg[row * 256 + col] = (col < 254) ? (acc[fi][fj][reg] + bv) : -1e30f;
      }
    }
  }
  __syncthreads();

  // ---- per-row log-softmax + NLL: wave w handles rows [w*8, w*8+8) ----
  float wsum = 0.f;
  int wcnt = 0;
#pragma unroll
  for (int rr = 0; rr < 8; ++rr) {
    const int r = uwid * 8 + rr;
    const float4 v4 = *(const float4*)&lg[r * 256 + lane * 4];
    float mx = fmaxf(fmaxf(v4.x, v4.y), fmaxf(v4.z, v4.w));
    for (int o = 32; o > 0; o >>= 1) mx = fmaxf(mx, __shfl_xor(mx, o));
    float s = expf(v4.x - mx) + expf(v4.y - mx) + expf(v4.z - mx) + expf(v4.w - mx);
    for (int o = 32; o > 0; o >>= 1) s += __shfl_xor(s, o);
    if (lane == 0) {
      const int lab = labels[m0 + r];
      if (lab != 0) {
        wsum += (logf(s) + mx) - lg[r * 256 + lab - 2];
        wcnt += 1;
      }
    }
  }
  if (lane == 0) {
    atomicAdd(loss_acc, (double)wsum);
    atomicAdd(cnt_acc, (unsigned long long)wcnt);
  }
}

__global__ void finalize_kernel(const double* __restrict__ loss_acc,
                                const unsigned long long* __restrict__ cnt_acc,
                                unsigned* __restrict__ out)
{
  unsigned long long cnt = cnt_acc[0];
  if (cnt == 0ull) cnt = 1ull;
  const float f = (float)(loss_acc[0] / (double)cnt);
  const unsigned u = __float_as_uint(f);
  const unsigned bf = (u + 0x7FFFu + ((u >> 16) & 1u)) >> 16;
  out[0] = (u & 0xFFFF0000u) | (bf & 0xFFFFu);
}

extern "C" void kernel_launch(void* const* d_in, const int* in_sizes, int n_in,
                              void* d_out, int out_size, void* d_ws, size_t ws_size,
                              hipStream_t stream)
{
  const int* src_seq = (const int*)d_in[0];
  const int* tgt_seq = (const int*)d_in[1];
  const float* enc_emb = (const float*)d_in[2];
  const float* enc_Wih = (const float*)d_in[3];
  const float* enc_Whh = (const float*)d_in[4];
  const float* enc_bih = (const float*)d_in[5];
  const float* enc_bhh = (const float*)d_in[6];
  const float* dec_emb = (const float*)d_in[7];
  const float* dec_Wih = (const float*)d_in[8];
  const float* dec_Whh = (const float*)d_in[9];
  const float* dec_bih = (const float*)d_in[10];
  const float* dec_bhh = (const float*)d_in[11];
  const float* unemb_W = (const float*)d_in[12];
  const float* unemb_b = (const float*)d_in[13];

  // ---- workspace carve-up (~64 MB) ----
  char* p = (char*)d_ws;
  ushort_t* hseq = (ushort_t*)p; p += (size_t)NSLOT * Bn * Hn * 2;   // 36 MB ring
  ushort_t* eWih = (ushort_t*)p; p += (size_t)3 * Hn * En * 2;
  ushort_t* eWhh = (ushort_t*)p; p += (size_t)3 * Hn * Hn * 2;
  ushort_t* dWih = (ushort_t*)p; p += (size_t)3 * Hn * En * 2;
  ushort_t* dWhh = (ushort_t*)p; p += (size_t)3 * Hn * Hn * 2;
  ushort_t* eEmb = (ushort_t*)p; p += (size_t)256 * En * 2;
  ushort_t* dEmb = (ushort_t*)p; p += (size_t)256 * En * 2;
  ushort_t* Wp   = (ushort_t*)p; p += (size_t)256 * Hn * 2;
  float* Pe = (float*)p; p += (size_t)256 * 3072 * 4;   // 3 MB
  float* Pd = (float*)p; p += (size_t)256 * 3072 * 4;   // 3 MB
  double* loss_acc = (double*)p;
  unsigned long long* cnt_acc = (unsigned long long*)(p + 8);

  ushort_t* slot7 = hseq + (size_t)7 * Bn * Hn;
  ushort_t* slot8 = hseq + (size_t)8 * Bn * Hn;

  hipMemsetAsync(slot7, 0, (size_t)Bn * Hn * 2, stream);
  hipMemsetAsync(loss_acc, 0, 16, stream);

  // ---- fp32 -> bf16 conversions ----
  struct { const float* src; ushort_t* dst; int n; } cv[6] = {
      {enc_Wih, eWih, 3 * Hn * En}, {enc_Whh, eWhh, 3 * Hn * Hn},
      {dec_Wih, dWih, 3 * Hn * En}, {dec_Whh, dWhh, 3 * Hn * Hn},
      {enc_emb, eEmb, 256 * En},    {dec_emb, dEmb, 256 * En}};
  for (int i = 0; i < 6; ++i) {
    int n4 = cv[i].n / 4;
    cvt_bf16_kernel<<<(n4 + 255) / 256, 256, 0, stream>>>(cv[i].src, cv[i].dst, n4);
  }
  cvt_pad_wu_kernel<<<(256 * Hn / 4 + 255) / 256, 256, 0, stream>>>(unemb_W, Wp);

  // ---- xp tables: P = emb @ Wih^T + bih ----
  {
    const dim3 pg(4, 48);
    pgemm_kernel<<<pg, 256, 0, stream>>>(eEmb, eWih, enc_bih, Pe);
    pgemm_kernel<<<pg, 256, 0, stream>>>(dEmb, dWih, dec_bih, Pd);
  }

  // ---- encoder: 64 steps, ping-pong slots 7/8 (bf16 h only) ----
  const ushort_t* in_b = slot7;
  for (int s = 0; s < 64; ++s) {
    ushort_t* out_b = (s & 1) ? slot7 : slot8;
    gru_step_mfma<<<512, 512, 0, stream>>>(src_seq + (size_t)s * Bn, Pe, eWhh, enc_bhh,
                                           in_b, out_b);
    in_b = out_b;
  }
  // encoder final: slot7 (s=63 odd)

  // ---- decoder: 47 steps; h_b history ring; batched unembed every 8 ----
  int done = 0;
  for (int s = 0; s < 47; ++s) {
    const ushort_t* din_b = (s == 0) ? slot7 : hseq + (size_t)((s - 1) % NSLOT) * Bn * Hn;
    ushort_t* dout_b = hseq + (size_t)(s % NSLOT) * Bn * Hn;
    gru_step_mfma<<<512, 512, 0, stream>>>(tgt_seq + (size_t)s * Bn, Pd, dWhh, dec_bhh,
                                           din_b, dout_b);
    if (s == 7 || s == 15 || s == 23 || s == 31 || s == 39 || s == 46) {
      const int cnt = s + 1 - done;
      unembed_batched<<<cnt * 64, 256, 0, stream>>>(hseq, done, Wp, unemb_b, tgt_seq,
                                                    loss_acc, cnt_acc);
      done = s + 1;
    }
  }

  finalize_kernel<<<1, 1, 0, stream>>>(loss_acc, cnt_acc, (unsigned*)d_out);
}

// Round 18
// 2582.176 us; speedup vs baseline: 1.2200x; 1.0041x over previous
//
#include <hip/hip_runtime.h>
#include <math.h>

typedef unsigned short ushort_t;
typedef __attribute__((ext_vector_type(8))) short short8;   // 8 bf16 (4 VGPRs)
typedef __attribute__((ext_vector_type(4))) float f32x4;    // MFMA C/D

#define Bn 2048
#define Hn 1024
#define En 512
#define NSLOT 9

__device__ __forceinline__ float sigmoidf_(float x) { return 1.f / (1.f + expf(-x)); }

__device__ __forceinline__ ushort_t bf16rn(float f) {
  unsigned u = __float_as_uint(f);
  return (ushort_t)((u + 0x7FFFu + ((u >> 16) & 1u)) >> 16);
}

__device__ __forceinline__ float bf2f(ushort_t u) {
  return __uint_as_float(((unsigned)u) << 16);
}

__global__ __launch_bounds__(256) void cvt_bf16_kernel(const float* __restrict__ in,
                                                       ushort_t* __restrict__ out, int n4) {
  int i = blockIdx.x * 256 + threadIdx.x;
  if (i < n4) {
    float4 v = ((const float4*)in)[i];
    ushort4 o;
    o.x = bf16rn(v.x); o.y = bf16rn(v.y); o.z = bf16rn(v.z); o.w = bf16rn(v.w);
    ((ushort4*)out)[i] = o;
  }
}

// unemb_W [254][1024] f32 -> [256][1024] bf16, rows 254/255 = 0
__global__ __launch_bounds__(256) void cvt_pad_wu_kernel(const float* __restrict__ src,
                                                         ushort_t* __restrict__ dst) {
  int i = blockIdx.x * 256 + threadIdx.x;
  if (i < 256 * Hn / 4) {
    float4 v = make_float4(0.f, 0.f, 0.f, 0.f);
    if (i * 4 < 254 * Hn) v = ((const float4*)src)[i];
    ushort4 o;
    o.x = bf16rn(v.x); o.y = bf16rn(v.y); o.z = bf16rn(v.z); o.w = bf16rn(v.w);
    ((ushort4*)dst)[i] = o;
  }
}

#define GLOAD(gsrc, ldst)                                                      \
  __builtin_amdgcn_global_load_lds(                                            \
      (const __attribute__((address_space(1))) unsigned int*)(gsrc),           \
      (__attribute__((address_space(3))) unsigned int*)(ldst), 16, 0, 0)

// counted-vmcnt pipeline barrier: drain own loads to N, raw barrier, pin sched.
#define PIPE_BAR(N)                                                            \
  asm volatile("s_waitcnt vmcnt(" #N ")" ::: "memory");                        \
  __builtin_amdgcn_s_barrier();                                                \
  __builtin_amdgcn_sched_barrier(0);

// bank swizzle for 64 B rows (4 chunks): chunk' = chunk ^ ((row>>1)&3)
#define SWZ(ROW, C) ((C) ^ (((ROW) >> 1) & 3))
// bank swizzle for 128 B rows (8 chunks): chunk' = chunk ^ (row&7)
#define SWZ64(ROW, C) ((C) ^ ((ROW) & 7))

// ---------------------------------------------------------------------------
// xp table: P[v][g] = sum_e emb[v][e]*Wih[g][e] + bih[g]   (v<256, g<3072)
// ---------------------------------------------------------------------------
__global__ __launch_bounds__(256) void pgemm_kernel(
    const ushort_t* __restrict__ A,    // [256][512] bf16 (emb)
    const ushort_t* __restrict__ Bw,   // [3072][512] bf16 (Wih)
    const float* __restrict__ bias,    // [3072] (bih)
    float* __restrict__ P)             // [256][3072] f32
{
  __shared__ __align__(16) ushort_t As[64 * 32];
  __shared__ __align__(16) ushort_t Bs[64 * 32];

  const int tid = threadIdx.x;
  const int lane = tid & 63;
  const int wid = tid >> 6;
  const int wr = wid >> 1, wc = wid & 1;
  const int m0 = blockIdx.x * 64;
  const int n0 = blockIdx.y * 64;

  const int srow = tid >> 2;
  const int sseg = SWZ(srow, tid & 3) * 8;
  const ushort_t* aP = A + (size_t)(m0 + srow) * En + sseg;
  const ushort_t* bP = Bw + (size_t)(n0 + srow) * En + sseg;

  const int kc = lane >> 4;
  const int ra0 = wr * 32 + (lane & 15), ra1 = ra0 + 16;
  const int rb0 = wc * 32 + (lane & 15), rb1 = rb0 + 16;
  const int aoff0 = ra0 * 32 + SWZ(ra0, kc) * 8;
  const int aoff1 = ra1 * 32 + SWZ(ra1, kc) * 8;
  const int boff0 = rb0 * 32 + SWZ(rb0, kc) * 8;
  const int boff1 = rb1 * 32 + SWZ(rb1, kc) * 8;

  const f32x4 zero = {0.f, 0.f, 0.f, 0.f};
  f32x4 acc[2][2] = {{zero, zero}, {zero, zero}};

  for (int k0 = 0; k0 < En; k0 += 32) {
    GLOAD(aP + k0, &As[wid * 512]);
    GLOAD(bP + k0, &Bs[wid * 512]);
    asm volatile("s_waitcnt vmcnt(0)" ::: "memory");
    __syncthreads();
    short8 a0 = *(const short8*)&As[aoff0];
    short8 a1 = *(const short8*)&As[aoff1];
    short8 b0 = *(const short8*)&Bs[boff0];
    short8 b1 = *(const short8*)&Bs[boff1];
    acc[0][0] = __builtin_amdgcn_mfma_f32_16x16x32_bf16(a0, b0, acc[0][0], 0, 0, 0);
    acc[0][1] = __builtin_amdgcn_mfma_f32_16x16x32_bf16(a0, b1, acc[0][1], 0, 0, 0);
    acc[1][0] = __builtin_amdgcn_mfma_f32_16x16x32_bf16(a1, b0, acc[1][0], 0, 0, 0);
    acc[1][1] = __builtin_amdgcn_mfma_f32_16x16x32_bf16(a1, b1, acc[1][1], 0, 0, 0);
    __syncthreads();
  }

  const int colb = n0 + wc * 32 + (lane & 15);
  const int rowb = m0 + wr * 32 + ((lane >> 4) << 2);
#pragma unroll
  for (int j = 0; j < 2; ++j) {
    const int g = colb + j * 16;
    const float bv = bias[g];
#pragma unroll
    for (int i = 0; i < 2; ++i)
#pragma unroll
      for (int reg = 0; reg < 4; ++reg)
        P[(size_t)(rowb + i * 16 + reg) * 3072 + g] = acc[i][j][reg] + bv;
  }
}

// ---------------------------------------------------------------------------
// GRU step v6 (R13/R17 known-good): tile 64(batch) x 64(h-col) x 3 gates,
// 512 threads (8 waves), 512 blocks => 2 blocks/CU, 16 waves/CU.
// BK=64, 16 K-iters, 2 LDS buffers, 2-phase counted pipeline.
// ---------------------------------------------------------------------------
#define KSTEP(BUF)                                                             \
  {                                                                            \
    short8 aF[2][2], bF[3][2];                                                 \
    _Pragma("unroll") for (int fi = 0; fi < 2; ++fi)                           \
        _Pragma("unroll") for (int h = 0; h < 2; ++h)                          \
            aF[fi][h] = *(const short8*)&As[BUF][aoff[fi][h]];                 \
    _Pragma("unroll") for (int g = 0; g < 3; ++g)                              \
        _Pragma("unroll") for (int h = 0; h < 2; ++h)                          \
            bF[g][h] = *(const short8*)&Bs[BUF][g][boff[h]];                   \
    __builtin_amdgcn_s_setprio(1);                                             \
    _Pragma("unroll") for (int h = 0; h < 2; ++h)                              \
        _Pragma("unroll") for (int g = 0; g < 3; ++g)                          \
            _Pragma("unroll") for (int fi = 0; fi < 2; ++fi)                   \
                acc[g][fi] = __builtin_amdgcn_mfma_f32_16x16x32_bf16(          \
                    aF[fi][h], bF[g][h], acc[g][fi], 0, 0, 0);                 \
    __builtin_amdgcn_s_setprio(0);                                             \
  }

#define GSTAGE(BUF, T)                                                         \
  {                                                                            \
    const int k0_ = (T) * 64;                                                  \
    GLOAD(aSrc + k0_, &As[BUF][wid * 512]);                                    \
    GLOAD(bSrc0 + k0_, &Bs[BUF][0][wid * 512]);                                \
    GLOAD(bSrc1 + k0_, &Bs[BUF][1][wid * 512]);                                \
    GLOAD(bSrc2 + k0_, &Bs[BUF][2][wid * 512]);                                \
  }

__global__ __launch_bounds__(512, 4) void gru_step_mfma(
    const int* __restrict__ seq_row,
    const float* __restrict__ P,          // [256][3072] f32 (xp + bih)
    const ushort_t* __restrict__ Whh,     // [3H][H] bf16
    const float* __restrict__ bhh,        // [3H]
    const ushort_t* __restrict__ h_in_b,  // [B][H] bf16
    ushort_t* __restrict__ h_out_b)       // [B][H] bf16
{
  __shared__ __align__(16) ushort_t As[2][64 * 64];      // 2 x 8 KB
  __shared__ __align__(16) ushort_t Bs[2][3][64 * 64];   // 2 x 24 KB
  __shared__ int toks[64];

  const int tid = threadIdx.x;
  const int lane = tid & 63;
  const int wid = tid >> 6;     // 0..7
  const int wr = wid & 1;       // 32-row band
  const int wc = wid >> 1;      // 16-col band (0..3)

  // XCD-affine swizzle: XCD q owns n-tiles {2q, 2q+1}. 512 blocks = 2/CU.
  const int bid = blockIdx.x;
  const int q = bid & 7, t_ = bid >> 3;          // t_ in 0..63
  const int n0 = ((q << 1) | (t_ & 1)) * 64;
  const int m0 = (t_ >> 1) * 64;                 // 32 m-tiles

  if (tid < 64) toks[tid] = seq_row[m0 + tid];
  __syncthreads();

  const int srow = tid >> 3;                     // 0..63
  const int sseg = SWZ64(srow, tid & 7) * 8;     // ushort offset in 64-elem row

  const ushort_t* aSrc  = h_in_b + (size_t)(m0 + srow) * Hn + sseg;
  const ushort_t* bSrc0 = Whh + (size_t)(0 * Hn + n0 + srow) * Hn + sseg;
  const ushort_t* bSrc1 = Whh + (size_t)(1 * Hn + n0 + srow) * Hn + sseg;
  const ushort_t* bSrc2 = Whh + (size_t)(2 * Hn + n0 + srow) * Hn + sseg;

  const int kc = lane >> 4;
  int aoff[2][2], boff[2];
#pragma unroll
  for (int fi = 0; fi < 2; ++fi) {
    const int ra = wr * 32 + fi * 16 + (lane & 15);
#pragma unroll
    for (int h = 0; h < 2; ++h) aoff[fi][h] = ra * 64 + SWZ64(ra, h * 4 + kc) * 8;
  }
  {
    const int rb = wc * 16 + (lane & 15);
#pragma unroll
    for (int h = 0; h < 2; ++h) boff[h] = rb * 64 + SWZ64(rb, h * 4 + kc) * 8;
  }

  const f32x4 zero = {0.f, 0.f, 0.f, 0.f};
  f32x4 acc[3][2];
#pragma unroll
  for (int g = 0; g < 3; ++g)
#pragma unroll
    for (int fi = 0; fi < 2; ++fi) acc[g][fi] = zero;

  // ---- 2-phase counted K-loop: 16 BK=64 steps over K=1024 ----
  GSTAGE(0, 0);
  int buf = 0;
  for (int t = 0; t < 15; ++t) {
    GSTAGE(buf ^ 1, t + 1);   // next stage in flight across the barrier
    PIPE_BAR(4)               // drain stage t only
    KSTEP(buf)
    buf ^= 1;
  }
  PIPE_BAR(0)                 // t=15
  KSTEP(buf)

  // ---- epilogue: xp gather from P + gates + state update (bf16 h only) ----
  const int n = n0 + wc * 16 + (lane & 15);
  const int rowl = wr * 32 + ((lane >> 4) << 2);   // local row base
  const float bhr = bhh[n];
  const float bhz = bhh[Hn + n];
  const float bhn = bhh[2 * Hn + n];
#pragma unroll
  for (int fi = 0; fi < 2; ++fi) {
#pragma unroll
    for (int reg = 0; reg < 4; ++reg) {
      const int lr = rowl + fi * 16 + reg;
      const int m = m0 + lr;
      const float* prow = P + (size_t)toks[lr] * 3072;
      const float xr = prow[n];
      const float xz = prow[Hn + n];
      const float xn = prow[2 * Hn + n];
      const float r = sigmoidf_(xr + acc[0][fi][reg] + bhr);
      const float z = sigmoidf_(xz + acc[1][fi][reg] + bhz);
      const float nn = tanhf(xn + r * (acc[2][fi][reg] + bhn));
      const float hv = bf2f(h_in_b[(size_t)m * Hn + n]);  // L2-hot re-read
      const float o = (1.f - z) * nn + z * hv;
      h_out_b[(size_t)m * Hn + n] = bf16rn(o);
    }
  }
}

// ---------------------------------------------------------------------------
// Unembed v4: 512 threads (8 waves = 2/SIMD), block = 64 output rows
// (32 rows from EACH of two adjacent steps, sharing one Wp staging) x 256
// cols.  BK=64, 16 iters, 2 bufs x 40 KB = 80 KB, uniform 5 loads/thread,
// counted vmcnt(5) depth-2 (the v6 GRU recipe).  Waves 0-3 = step-A rows,
// waves 4-7 = step-B rows.  64 KB logits overlay.  4 pairs x 64 blocks/disp.
// ---------------------------------------------------------------------------
#define USTAGE(BUF, T)                                                         \
  {                                                                            \
    const int k0_ = (T) * 64;                                                  \
    GLOAD(ha + k0_, AsU(BUF) + wid * 512);                                     \
    GLOAD(w0 + k0_, BsU(BUF) + 0 * 4096 + wid * 512);                          \
    GLOAD(w1 + k0_, BsU(BUF) + 1 * 4096 + wid * 512);                          \
    GLOAD(w2 + k0_, BsU(BUF) + 2 * 4096 + wid * 512);                          \
    GLOAD(w3 + k0_, BsU(BUF) + 3 * 4096 + wid * 512);                          \
  }

#define UKSTEP(BUF)                                                            \
  {                                                                            \
    short8 a_[2][2], b_[4][2];                                                 \
    _Pragma("unroll") for (int fi = 0; fi < 2; ++fi)                           \
        _Pragma("unroll") for (int h = 0; h < 2; ++h)                          \
            a_[fi][h] = *(const short8*)(AsU(BUF) + uaoff[fi][h]);             \
    _Pragma("unroll") for (int fj = 0; fj < 4; ++fj)                           \
        _Pragma("unroll") for (int h = 0; h < 2; ++h)                          \
            b_[fj][h] = *(const short8*)(BsU(BUF) + uboff[fj][h]);             \
    __builtin_amdgcn_s_setprio(1);                                             \
    _Pragma("unroll") for (int h = 0; h < 2; ++h)                              \
        _Pragma("unroll") for (int fi = 0; fi < 2; ++fi)                       \
            _Pragma("unroll") for (int fj = 0; fj < 4; ++fj)                   \
                acc[fi][fj] = __builtin_amdgcn_mfma_f32_16x16x32_bf16(         \
                    a_[fi][h], b_[fj][h], acc[fi][fj], 0, 0, 0);               \
    __builtin_amdgcn_s_setprio(0);                                             \
  }

__global__ __launch_bounds__(512) void unembed_batched(
    const ushort_t* __restrict__ hseq,  // [NSLOT][B][H] bf16 ring
    int s0, int scnt,
    const ushort_t* __restrict__ Wp,    // [256][H] bf16 (rows 254/255 = 0)
    const float* __restrict__ bu,       // [254]
    const int* __restrict__ tgt_seq,    // [S_tgt][B]
    double* __restrict__ loss_acc,
    unsigned long long* __restrict__ cnt_acc)
{
  // carve: A bufs 2 x 8 KB at [0,16K) | B bufs 2 x 32 KB at [16K,80K)
  __shared__ __align__(16) char usmem[80 * 1024];
#define AsU(BUF) ((ushort_t*)usmem + (BUF) * 4096)
#define BsU(BUF) ((ushort_t*)(usmem + 16 * 1024) + (BUF) * 16384)
  float* lg = (float*)usmem;  // [64][256] f32 = 64 KB overlay (post-staging)

  const int tid = threadIdx.x;
  const int lane = tid & 63;
  const int wid = tid >> 6;      // 0..7
  const int wr = wid >> 2;       // 0 = step-A rows, 1 = step-B rows
  const int wc = wid & 3;        // 64-col band

  const int pair = blockIdx.x >> 6;               // 64 blocks per pair
  const int m0 = (blockIdx.x & 63) * 32;
  const int sA = s0 + 2 * pair;
  const int has2 = (2 * pair + 1) < scnt;
  const int slotA = sA % NSLOT;
  const int slotB = has2 ? (sA + 1) % NSLOT : slotA;

  const int srow = tid >> 3;                      // 0..63
  const int sseg = SWZ64(srow, tid & 7) * 8;

  const ushort_t* hbase =
      hseq + (size_t)(srow < 32 ? slotA : slotB) * Bn * Hn;
  const ushort_t* ha = hbase + (size_t)(m0 + (srow & 31)) * Hn + sseg;
  const ushort_t* w0 = Wp + (size_t)(0 * 64 + srow) * Hn + sseg;
  const ushort_t* w1 = Wp + (size_t)(1 * 64 + srow) * Hn + sseg;
  const ushort_t* w2 = Wp + (size_t)(2 * 64 + srow) * Hn + sseg;
  const ushort_t* w3 = Wp + (size_t)(3 * 64 + srow) * Hn + sseg;

  const int kc = lane >> 4;
  int uaoff[2][2], uboff[4][2];
#pragma unroll
  for (int fi = 0; fi < 2; ++fi) {
    const int ra = wr * 32 + fi * 16 + (lane & 15);
#pragma unroll
    for (int h = 0; h < 2; ++h) uaoff[fi][h] = ra * 64 + SWZ64(ra, h * 4 + kc) * 8;
  }
#pragma unroll
  for (int fj = 0; fj < 4; ++fj) {
    const int rb = wc * 64 + fj * 16 + (lane & 15);
#pragma unroll
    for (int h = 0; h < 2; ++h) uboff[fj][h] = rb * 64 + SWZ64(rb, h * 4 + kc) * 8;
  }

  const f32x4 zero = {0.f, 0.f, 0.f, 0.f};
  f32x4 acc[2][4];
#pragma unroll
  for (int fi = 0; fi < 2; ++fi)
#pragma unroll
    for (int fj = 0; fj < 4; ++fj) acc[fi][fj] = zero;

  // ---- 2-phase counted K-loop: 16 BK=64 steps over K=1024 ----
  USTAGE(0, 0);
  int buf = 0;
  for (int t = 0; t < 15; ++t) {
    USTAGE(buf ^ 1, t + 1);   // next stage in flight across the barrier
    PIPE_BAR(5)               // drain stage t only
    UKSTEP(buf)
    buf ^= 1;
  }
  PIPE_BAR(0)                 // t=15
  UKSTEP(buf)

  // ---- logits -> LDS overlay (bias + mask pad cols) ----
  __syncthreads();  // all ds_reads of staging done; safe to overwrite with lg
#pragma unroll
  for (int fj = 0; fj < 4; ++fj) {
    const int col = wc * 64 + fj * 16 + (lane & 15);
    const float bv = (col < 254) ? bu[col] : 0.f;
#pragma unroll
    for (int fi = 0; fi < 2; ++fi) {
#pragma unroll
      for (int reg = 0; reg < 4; ++reg) {
        const int row = wr * 32 + fi * 16 + (lane >> 4) * 4 + reg;
        lg[row * 256 + col] = (col < 254) ? (acc[fi][fj][reg] + bv) : -1e30f;
      }
    }
  }
  __syncthreads();

  // ---- per-row log-softmax + NLL: wave w handles rows [w*8, w*8+8) ----
  // rows 0-31 = step A; rows 32-63 = step B (skip if !has2)
  float wsum = 0.f;
  int wcnt = 0;
  if (wid < 4 || has2) {
    const int isB = (wid >= 4);
    const int* labels = tgt_seq + (size_t)(sA + 1 + isB) * Bn;
#pragma unroll
    for (int rr = 0; rr < 8; ++rr) {
      const int r = wid * 8 + rr;
      const float4 v4 = *(const float4*)&lg[r * 256 + lane * 4];
      float mx = fmaxf(fmaxf(v4.x, v4.y), fmaxf(v4.z, v4.w));
      for (int o = 32; o > 0; o >>= 1) mx = fmaxf(mx, __shfl_xor(mx, o));
      float s = expf(v4.x - mx) + expf(v4.y - mx) + expf(v4.z - mx) + expf(v4.w - mx);
      for (int o = 32; o > 0; o >>= 1) s += __shfl_xor(s, o);
      if (lane == 0) {
        const int lab = labels[m0 + (r & 31)];
        if (lab != 0) {
          wsum += (logf(s) + mx) - lg[r * 256 + lab - 2];
          wcnt += 1;
        }
      }
    }
  }
  if (lane == 0 && wcnt > 0) {
    atomicAdd(loss_acc, (double)wsum);
    atomicAdd(cnt_acc, (unsigned long long)wcnt);
  }
}

__global__ void finalize_kernel(const double* __restrict__ loss_acc,
                                const unsigned long long* __restrict__ cnt_acc,
                                unsigned* __restrict__ out)
{
  unsigned long long cnt = cnt_acc[0];
  if (cnt == 0ull) cnt = 1ull;
  const float f = (float)(loss_acc[0] / (double)cnt);
  const unsigned u = __float_as_uint(f);
  const unsigned bf = (u + 0x7FFFu + ((u >> 16) & 1u)) >> 16;
  out[0] = (u & 0xFFFF0000u) | (bf & 0xFFFFu);
}

extern "C" void kernel_launch(void* const* d_in, const int* in_sizes, int n_in,
                              void* d_out, int out_size, void* d_ws, size_t ws_size,
                              hipStream_t stream)
{
  const int* src_seq = (const int*)d_in[0];
  const int* tgt_seq = (const int*)d_in[1];
  const float* enc_emb = (const float*)d_in[2];
  const float* enc_Wih = (const float*)d_in[3];
  const float* enc_Whh = (const float*)d_in[4];
  const float* enc_bih = (const float*)d_in[5];
  const float* enc_bhh = (const float*)d_in[6];
  const float* dec_emb = (const float*)d_in[7];
  const float* dec_Wih = (const float*)d_in[8];
  const float* dec_Whh = (const float*)d_in[9];
  const float* dec_bih = (const float*)d_in[10];
  const float* dec_bhh = (const float*)d_in[11];
  const float* unemb_W = (const float*)d_in[12];
  const float* unemb_b = (const float*)d_in[13];

  // ---- workspace carve-up (~64 MB) ----
  char* p = (char*)d_ws;
  ushort_t* hseq = (ushort_t*)p; p += (size_t)NSLOT * Bn * Hn * 2;   // 36 MB ring
  ushort_t* eWih = (ushort_t*)p; p += (size_t)3 * Hn * En * 2;
  ushort_t* eWhh = (ushort_t*)p; p += (size_t)3 * Hn * Hn * 2;
  ushort_t* dWih = (ushort_t*)p; p += (size_t)3 * Hn * En * 2;
  ushort_t* dWhh = (ushort_t*)p; p += (size_t)3 * Hn * Hn * 2;
  ushort_t* eEmb = (ushort_t*)p; p += (size_t)256 * En * 2;
  ushort_t* dEmb = (ushort_t*)p; p += (size_t)256 * En * 2;
  ushort_t* Wp   = (ushort_t*)p; p += (size_t)256 * Hn * 2;
  float* Pe = (float*)p; p += (size_t)256 * 3072 * 4;   // 3 MB
  float* Pd = (float*)p; p += (size_t)256 * 3072 * 4;   // 3 MB
  double* loss_acc = (double*)p;
  unsigned long long* cnt_acc = (unsigned long long*)(p + 8);

  ushort_t* slot7 = hseq + (size_t)7 * Bn * Hn;
  ushort_t* slot8 = hseq + (size_t)8 * Bn * Hn;

  hipMemsetAsync(slot7, 0, (size_t)Bn * Hn * 2, stream);
  hipMemsetAsync(loss_acc, 0, 16, stream);

  // ---- fp32 -> bf16 conversions ----
  struct { const float* src; ushort_t* dst; int n; } cv[6] = {
      {enc_Wih, eWih, 3 * Hn * En}, {enc_Whh, eWhh, 3 * Hn * Hn},
      {dec_Wih, dWih, 3 * Hn * En}, {dec_Whh, dWhh, 3 * Hn * Hn},
      {enc_emb, eEmb, 256 * En},    {dec_emb, dEmb, 256 * En}};
  for (int i = 0; i < 6; ++i) {
    int n4 = cv[i].n / 4;
    cvt_bf16_kernel<<<(n4 + 255) / 256, 256, 0, stream>>>(cv[i].src, cv[i].dst, n4);
  }
  cvt_pad_wu_kernel<<<(256 * Hn / 4 + 255) / 256, 256, 0, stream>>>(unemb_W, Wp);

  // ---- xp tables: P = emb @ Wih^T + bih ----
  {
    const dim3 pg(4, 48);
    pgemm_kernel<<<pg, 256, 0, stream>>>(eEmb, eWih, enc_bih, Pe);
    pgemm_kernel<<<pg, 256, 0, stream>>>(dEmb, dWih, dec_bih, Pd);
  }

  // ---- encoder: 64 steps, ping-pong slots 7/8 (bf16 h only) ----
  const ushort_t* in_b = slot7;
  for (int s = 0; s < 64; ++s) {
    ushort_t* out_b = (s & 1) ? slot7 : slot8;
    gru_step_mfma<<<512, 512, 0, stream>>>(src_seq + (size_t)s * Bn, Pe, eWhh, enc_bhh,
                                           in_b, out_b);
    in_b = out_b;
  }
  // encoder final: slot7 (s=63 odd)

  // ---- decoder: 47 steps; h_b history ring; paired unembed every 8 ----
  int done = 0;
  for (int s = 0; s < 47; ++s) {
    const ushort_t* din_b = (s == 0) ? slot7 : hseq + (size_t)((s - 1) % NSLOT) * Bn * Hn;
    ushort_t* dout_b = hseq + (size_t)(s % NSLOT) * Bn * Hn;
    gru_step_mfma<<<512, 512, 0, stream>>>(tgt_seq + (size_t)s * Bn, Pd, dWhh, dec_bhh,
                                           din_b, dout_b);
    if (s == 7 || s == 15 || s == 23 || s == 31 || s == 39 || s == 46) {
      const int cnt = s + 1 - done;
      const int npair = (cnt + 1) / 2;
      unembed_batched<<<npair * 64, 512, 0, stream>>>(hseq, done, cnt, Wp, unemb_b,
                                                      tgt_seq, loss_acc, cnt_acc);
      done = s + 1;
    }
  }

  finalize_kernel<<<1, 1, 0, stream>>>(loss_acc, cnt_acc, (unsigned*)d_out);
}

// Round 19
// 2483.346 us; speedup vs baseline: 1.2686x; 1.0398x over previous
//
#include <hip/hip_runtime.h>
#include <math.h>

typedef unsigned short ushort_t;
typedef __attribute__((ext_vector_type(8))) short short8;   // 8 bf16 (4 VGPRs)
typedef __attribute__((ext_vector_type(4))) float f32x4;    // MFMA C/D

#define Bn 2048
#define Hn 1024
#define En 512
#define NSLOT 9

__device__ __forceinline__ float sigmoidf_(float x) { return 1.f / (1.f + expf(-x)); }

__device__ __forceinline__ ushort_t bf16rn(float f) {
  unsigned u = __float_as_uint(f);
  return (ushort_t)((u + 0x7FFFu + ((u >> 16) & 1u)) >> 16);
}

__device__ __forceinline__ float bf2f(ushort_t u) {
  return __uint_as_float(((unsigned)u) << 16);
}

__global__ __launch_bounds__(256) void cvt_bf16_kernel(const float* __restrict__ in,
                                                       ushort_t* __restrict__ out, int n4) {
  int i = blockIdx.x * 256 + threadIdx.x;
  if (i < n4) {
    float4 v = ((const float4*)in)[i];
    ushort4 o;
    o.x = bf16rn(v.x); o.y = bf16rn(v.y); o.z = bf16rn(v.z); o.w = bf16rn(v.w);
    ((ushort4*)out)[i] = o;
  }
}

// unemb_W [254][1024] f32 -> [256][1024] bf16, rows 254/255 = 0
__global__ __launch_bounds__(256) void cvt_pad_wu_kernel(const float* __restrict__ src,
                                                         ushort_t* __restrict__ dst) {
  int i = blockIdx.x * 256 + threadIdx.x;
  if (i < 256 * Hn / 4) {
    float4 v = make_float4(0.f, 0.f, 0.f, 0.f);
    if (i * 4 < 254 * Hn) v = ((const float4*)src)[i];
    ushort4 o;
    o.x = bf16rn(v.x); o.y = bf16rn(v.y); o.z = bf16rn(v.z); o.w = bf16rn(v.w);
    ((ushort4*)dst)[i] = o;
  }
}

#define GLOAD(gsrc, ldst)                                                      \
  __builtin_amdgcn_global_load_lds(                                            \
      (const __attribute__((address_space(1))) unsigned int*)(gsrc),           \
      (__attribute__((address_space(3))) unsigned int*)(ldst), 16, 0, 0)

// counted-vmcnt pipeline barrier: drain own loads to N, raw barrier, pin sched.
#define PIPE_BAR(N)                                                            \
  asm volatile("s_waitcnt vmcnt(" #N ")" ::: "memory");                        \
  __builtin_amdgcn_s_barrier();                                                \
  __builtin_amdgcn_sched_barrier(0);

// bank swizzle for 64 B rows (4 chunks): chunk' = chunk ^ ((row>>1)&3)
#define SWZ(ROW, C) ((C) ^ (((ROW) >> 1) & 3))
// bank swizzle for 128 B rows (8 chunks): chunk' = chunk ^ (row&7)
#define SWZ64(ROW, C) ((C) ^ ((ROW) & 7))

// ---------------------------------------------------------------------------
// xp table: P[v][g] = sum_e emb[v][e]*Wih[g][e] + bih[g]   (v<256, g<3072)
// ---------------------------------------------------------------------------
__global__ __launch_bounds__(256) void pgemm_kernel(
    const ushort_t* __restrict__ A,    // [256][512] bf16 (emb)
    const ushort_t* __restrict__ Bw,   // [3072][512] bf16 (Wih)
    const float* __restrict__ bias,    // [3072] (bih)
    float* __restrict__ P)             // [256][3072] f32
{
  __shared__ __align__(16) ushort_t As[64 * 32];
  __shared__ __align__(16) ushort_t Bs[64 * 32];

  const int tid = threadIdx.x;
  const int lane = tid & 63;
  const int wid = tid >> 6;
  const int wr = wid >> 1, wc = wid & 1;
  const int m0 = blockIdx.x * 64;
  const int n0 = blockIdx.y * 64;

  const int srow = tid >> 2;
  const int sseg = SWZ(srow, tid & 3) * 8;
  const ushort_t* aP = A + (size_t)(m0 + srow) * En + sseg;
  const ushort_t* bP = Bw + (size_t)(n0 + srow) * En + sseg;

  const int kc = lane >> 4;
  const int ra0 = wr * 32 + (lane & 15), ra1 = ra0 + 16;
  const int rb0 = wc * 32 + (lane & 15), rb1 = rb0 + 16;
  const int aoff0 = ra0 * 32 + SWZ(ra0, kc) * 8;
  const int aoff1 = ra1 * 32 + SWZ(ra1, kc) * 8;
  const int boff0 = rb0 * 32 + SWZ(rb0, kc) * 8;
  const int boff1 = rb1 * 32 + SWZ(rb1, kc) * 8;

  const f32x4 zero = {0.f, 0.f, 0.f, 0.f};
  f32x4 acc[2][2] = {{zero, zero}, {zero, zero}};

  for (int k0 = 0; k0 < En; k0 += 32) {
    GLOAD(aP + k0, &As[wid * 512]);
    GLOAD(bP + k0, &Bs[wid * 512]);
    asm volatile("s_waitcnt vmcnt(0)" ::: "memory");
    __syncthreads();
    short8 a0 = *(const short8*)&As[aoff0];
    short8 a1 = *(const short8*)&As[aoff1];
    short8 b0 = *(const short8*)&Bs[boff0];
    short8 b1 = *(const short8*)&Bs[boff1];
    acc[0][0] = __builtin_amdgcn_mfma_f32_16x16x32_bf16(a0, b0, acc[0][0], 0, 0, 0);
    acc[0][1] = __builtin_amdgcn_mfma_f32_16x16x32_bf16(a0, b1, acc[0][1], 0, 0, 0);
    acc[1][0] = __builtin_amdgcn_mfma_f32_16x16x32_bf16(a1, b0, acc[1][0], 0, 0, 0);
    acc[1][1] = __builtin_amdgcn_mfma_f32_16x16x32_bf16(a1, b1, acc[1][1], 0, 0, 0);
    __syncthreads();
  }

  const int colb = n0 + wc * 32 + (lane & 15);
  const int rowb = m0 + wr * 32 + ((lane >> 4) << 2);
#pragma unroll
  for (int j = 0; j < 2; ++j) {
    const int g = colb + j * 16;
    const float bv = bias[g];
#pragma unroll
    for (int i = 0; i < 2; ++i)
#pragma unroll
      for (int reg = 0; reg < 4; ++reg)
        P[(size_t)(rowb + i * 16 + reg) * 3072 + g] = acc[i][j][reg] + bv;
  }
}

// ---------------------------------------------------------------------------
// GRU step v6 (R13 known-good): tile 64(batch) x 64(h-col) x 3 gates,
// 512 threads (8 waves), 512 blocks => 2 blocks/CU, 16 waves/CU.
// BK=64, 16 K-iters, 2 LDS buffers, 2-phase counted pipeline:
// issue stage t+1 -> vmcnt(4) (drain t, keep t+1 in flight) -> barrier -> MFMA.
// ---------------------------------------------------------------------------
#define KSTEP(BUF)                                                             \
  {                                                                            \
    short8 aF[2][2], bF[3][2];                                                 \
    _Pragma("unroll") for (int fi = 0; fi < 2; ++fi)                           \
        _Pragma("unroll") for (int h = 0; h < 2; ++h)                          \
            aF[fi][h] = *(const short8*)&As[BUF][aoff[fi][h]];                 \
    _Pragma("unroll") for (int g = 0; g < 3; ++g)                              \
        _Pragma("unroll") for (int h = 0; h < 2; ++h)                          \
            bF[g][h] = *(const short8*)&Bs[BUF][g][boff[h]];                   \
    __builtin_amdgcn_s_setprio(1);                                             \
    _Pragma("unroll") for (int h = 0; h < 2; ++h)                              \
        _Pragma("unroll") for (int g = 0; g < 3; ++g)                          \
            _Pragma("unroll") for (int fi = 0; fi < 2; ++fi)                   \
                acc[g][fi] = __builtin_amdgcn_mfma_f32_16x16x32_bf16(          \
                    aF[fi][h], bF[g][h], acc[g][fi], 0, 0, 0);                 \
    __builtin_amdgcn_s_setprio(0);                                             \
  }

#define GSTAGE(BUF, T)                                                         \
  {                                                                            \
    const int k0_ = (T) * 64;                                                  \
    GLOAD(aSrc + k0_, &As[BUF][wid * 512]);                                    \
    GLOAD(bSrc0 + k0_, &Bs[BUF][0][wid * 512]);                                \
    GLOAD(bSrc1 + k0_, &Bs[BUF][1][wid * 512]);                                \
    GLOAD(bSrc2 + k0_, &Bs[BUF][2][wid * 512]);                                \
  }

__global__ __launch_bounds__(512, 4) void gru_step_mfma(
    const int* __restrict__ seq_row,
    const float* __restrict__ P,          // [256][3072] f32 (xp + bih)
    const ushort_t* __restrict__ Whh,     // [3H][H] bf16
    const float* __restrict__ bhh,        // [3H]
    const ushort_t* __restrict__ h_in_b,  // [B][H] bf16
    ushort_t* __restrict__ h_out_b)       // [B][H] bf16
{
  __shared__ __align__(16) ushort_t As[2][64 * 64];      // 2 x 8 KB
  __shared__ __align__(16) ushort_t Bs[2][3][64 * 64];   // 2 x 24 KB
  __shared__ int toks[64];

  const int tid = threadIdx.x;
  const int lane = tid & 63;
  const int wid = tid >> 6;     // 0..7
  const int wr = wid & 1;       // 32-row band
  const int wc = wid >> 1;      // 16-col band (0..3)

  // XCD-affine swizzle: XCD q owns n-tiles {2q, 2q+1}. 512 blocks = 2/CU.
  const int bid = blockIdx.x;
  const int q = bid & 7, t_ = bid >> 3;          // t_ in 0..63
  const int n0 = ((q << 1) | (t_ & 1)) * 64;
  const int m0 = (t_ >> 1) * 64;                 // 32 m-tiles

  if (tid < 64) toks[tid] = seq_row[m0 + tid];
  __syncthreads();

  const int srow = tid >> 3;                     // 0..63
  const int sseg = SWZ64(srow, tid & 7) * 8;     // ushort offset in 64-elem row

  const ushort_t* aSrc  = h_in_b + (size_t)(m0 + srow) * Hn + sseg;
  const ushort_t* bSrc0 = Whh + (size_t)(0 * Hn + n0 + srow) * Hn + sseg;
  const ushort_t* bSrc1 = Whh + (size_t)(1 * Hn + n0 + srow) * Hn + sseg;
  const ushort_t* bSrc2 = Whh + (size_t)(2 * Hn + n0 + srow) * Hn + sseg;

  const int kc = lane >> 4;
  int aoff[2][2], boff[2];
#pragma unroll
  for (int fi = 0; fi < 2; ++fi) {
    const int ra = wr * 32 + fi * 16 + (lane & 15);
#pragma unroll
    for (int h = 0; h < 2; ++h) aoff[fi][h] = ra * 64 + SWZ64(ra, h * 4 + kc) * 8;
  }
  {
    const int rb = wc * 16 + (lane & 15);
#pragma unroll
    for (int h = 0; h < 2; ++h) boff[h] = rb * 64 + SWZ64(rb, h * 4 + kc) * 8;
  }

  const f32x4 zero = {0.f, 0.f, 0.f, 0.f};
  f32x4 acc[3][2];
#pragma unroll
  for (int g = 0; g < 3; ++g)
#pragma unroll
    for (int fi = 0; fi < 2; ++fi) acc[g][fi] = zero;

  // ---- 2-phase counted K-loop: 16 BK=64 steps over K=1024 ----
  GSTAGE(0, 0);
  int buf = 0;
  for (int t = 0; t < 15; ++t) {
    GSTAGE(buf ^ 1, t + 1);   // next stage in flight across the barrier
    PIPE_BAR(4)               // drain stage t only
    KSTEP(buf)
    buf ^= 1;
  }
  PIPE_BAR(0)                 // t=15
  KSTEP(buf)

  // ---- epilogue: xp gather from P + gates + state update (bf16 h only) ----
  const int n = n0 + wc * 16 + (lane & 15);
  const int rowl = wr * 32 + ((lane >> 4) << 2);   // local row base
  const float bhr = bhh[n];
  const float bhz = bhh[Hn + n];
  const float bhn = bhh[2 * Hn + n];
#pragma unroll
  for (int fi = 0; fi < 2; ++fi) {
#pragma unroll
    for (int reg = 0; reg < 4; ++reg) {
      const int lr = rowl + fi * 16 + reg;
      const int m = m0 + lr;
      const float* prow = P + (size_t)toks[lr] * 3072;
      const float xr = prow[n];
      const float xz = prow[Hn + n];
      const float xn = prow[2 * Hn + n];
      const float r = sigmoidf_(xr + acc[0][fi][reg] + bhr);
      const float z = sigmoidf_(xz + acc[1][fi][reg] + bhz);
      const float nn = tanhf(xn + r * (acc[2][fi][reg] + bhn));
      const float hv = bf2f(h_in_b[(size_t)m * Hn + n]);  // L2-hot re-read
      const float o = (1.f - z) * nn + z * hv;
      h_out_b[(size_t)m * Hn + n] = bf16rn(o);
    }
  }
}

// ---------------------------------------------------------------------------
// Batched unembed (R13 known-good): block = 64 rows x 256 cols, K=1024,
// 4 buffers, depth-3 counted vmcnt(10), uniform 5 loads/thread/stage.
// 32 blocks per decoder step; logits buffer aliased over staging LDS.
// ---------------------------------------------------------------------------
#define USTAGE(BUF, T)                                                         \
  {                                                                            \
    const int k0_ = (T) * 32;                                                  \
    GLOAD(ha + k0_, AsU(BUF) + uwid * 512);                                    \
    GLOAD(w0 + k0_, BsU(BUF) + 0 * 2048 + uwid * 512);                         \
    GLOAD(w1 + k0_, BsU(BUF) + 1 * 2048 + uwid * 512);                         \
    GLOAD(w2 + k0_, BsU(BUF) + 2 * 2048 + uwid * 512);                         \
    GLOAD(w3 + k0_, BsU(BUF) + 3 * 2048 + uwid * 512);                         \
  }

#define UPIPE_BAR(N)                                                           \
  asm volatile("s_waitcnt vmcnt(" #N ")" ::: "memory");                        \
  __builtin_amdgcn_s_barrier();                                                \
  __builtin_amdgcn_sched_barrier(0);

#define UKSTEP(BUF)                                                            \
  {                                                                            \
    short8 a_[4], b_[4];                                                       \
    _Pragma("unroll") for (int fi = 0; fi < 4; ++fi)                           \
        a_[fi] = *(const short8*)(AsU(BUF) + uaoff[fi]);                       \
    _Pragma("unroll") for (int fj = 0; fj < 4; ++fj)                           \
        b_[fj] = *(const short8*)(BsU(BUF) + uboff[fj]);                       \
    _Pragma("unroll") for (int fi = 0; fi < 4; ++fi)                           \
        _Pragma("unroll") for (int fj = 0; fj < 4; ++fj)                       \
            acc[fi][fj] = __builtin_amdgcn_mfma_f32_16x16x32_bf16(             \
                a_[fi], b_[fj], acc[fi][fj], 0, 0, 0);                         \
  }

__global__ __launch_bounds__(256) void unembed_batched(
    const ushort_t* __restrict__ hseq,  // [NSLOT][B][H] bf16 ring
    int s0,
    const ushort_t* __restrict__ Wp,    // [256][H] bf16 (rows 254/255 = 0)
    const float* __restrict__ bu,       // [254]
    const int* __restrict__ tgt_seq,    // [S_tgt][B]
    double* __restrict__ loss_acc,
    unsigned long long* __restrict__ cnt_acc)
{
  __shared__ __align__(16) char usmem[16 * 1024 + 64 * 1024];  // 80 KB
#define AsU(BUF) ((ushort_t*)usmem + (BUF) * 2048)             // 4 x 4 KB
#define BsU(BUF) ((ushort_t*)(usmem + 16 * 1024) + (BUF) * 8192)  // 4 x 16 KB
  float* lg = (float*)usmem;                                   // [64][256] overlay

  const int tid = threadIdx.x;
  const int lane = tid & 63;
  const int uwid = tid >> 6;

  const int step = blockIdx.x >> 5;                 // 32 blocks per step
  const int slot = (s0 + step) % NSLOT;
  const int m0 = (blockIdx.x & 31) * 64;
  const ushort_t* h_b = hseq + (size_t)slot * Bn * Hn;
  const int* labels = tgt_seq + (size_t)(s0 + step + 1) * Bn;

  const int srow = tid >> 2;
  const int sseg = SWZ(srow, tid & 3) * 8;

  const ushort_t* ha = h_b + (size_t)(m0 + srow) * Hn + sseg;
  const ushort_t* w0 = Wp + (size_t)(0 * 64 + srow) * Hn + sseg;
  const ushort_t* w1 = Wp + (size_t)(1 * 64 + srow) * Hn + sseg;
  const ushort_t* w2 = Wp + (size_t)(2 * 64 + srow) * Hn + sseg;
  const ushort_t* w3 = Wp + (size_t)(3 * 64 + srow) * Hn + sseg;

  const int kc = lane >> 4;
  int uaoff[4], uboff[4];
#pragma unroll
  for (int fi = 0; fi < 4; ++fi) {
    const int ra = fi * 16 + (lane & 15);
    uaoff[fi] = ra * 32 + SWZ(ra, kc) * 8;
  }
#pragma unroll
  for (int fj = 0; fj < 4; ++fj) {
    const int rb = uwid * 64 + fj * 16 + (lane & 15);
    uboff[fj] = rb * 32 + SWZ(rb, kc) * 8;
  }

  const f32x4 zero = {0.f, 0.f, 0.f, 0.f};
  f32x4 acc[4][4];
#pragma unroll
  for (int fi = 0; fi < 4; ++fi)
#pragma unroll
    for (int fj = 0; fj < 4; ++fj) acc[fi][fj] = zero;

  USTAGE(0, 0);
  USTAGE(1, 1);
  USTAGE(2, 2);
  for (int t = 0; t < 29; ++t) {
    UPIPE_BAR(10)
    USTAGE((t + 3) & 3, t + 3);
    UKSTEP(t & 3)
  }
  UPIPE_BAR(10)  // t=29
  UKSTEP(1)
  UPIPE_BAR(5)   // t=30
  UKSTEP(2)
  UPIPE_BAR(0)   // t=31
  UKSTEP(3)

  // ---- logits -> LDS overlay (bias + mask pad cols) ----
  __syncthreads();  // all ds_reads of staging done; safe to overwrite with lg
#pragma unroll
  for (int fj = 0; fj < 4; ++fj) {
    const int col = uwid * 64 + fj * 16 + (lane & 15);
    const float bv = (col < 254) ? bu[col] : 0.f;
#pragma unroll
    for (int fi = 0; fi < 4; ++fi) {
#pragma unroll
      for (int reg = 0; reg < 4; ++reg) {
        const int row = fi * 16 + (lane >> 4) * 4 + reg;
        lg[row * 256 + col] = (col < 254) ? (acc[fi][fj][reg] + bv) : -1e30f;
      }
    }
  }
  __syncthreads();

  // ---- per-row log-softmax + NLL: wave w handles rows [w*16, w*16+16) ----
  float wsum = 0.f;
  int wcnt = 0;
#pragma unroll
  for (int rr = 0; rr < 16; ++rr) {
    const int r = uwid * 16 + rr;
    const float4 v4 = *(const float4*)&lg[r * 256 + lane * 4];
    float mx = fmaxf(fmaxf(v4.x, v4.y), fmaxf(v4.z, v4.w));
    for (int o = 32; o > 0; o >>= 1) mx = fmaxf(mx, __shfl_xor(mx, o));
    float s = expf(v4.x - mx) + expf(v4.y - mx) + expf(v4.z - mx) + expf(v4.w - mx);
    for (int o = 32; o > 0; o >>= 1) s += __shfl_xor(s, o);
    if (lane == 0) {
      const int lab = labels[m0 + r];
      if (lab != 0) {
        wsum += (logf(s) + mx) - lg[r * 256 + lab - 2];
        wcnt += 1;
      }
    }
  }
  if (lane == 0) {
    atomicAdd(loss_acc, (double)wsum);
    atomicAdd(cnt_acc, (unsigned long long)wcnt);
  }
}

__global__ void finalize_kernel(const double* __restrict__ loss_acc,
                                const unsigned long long* __restrict__ cnt_acc,
                                unsigned* __restrict__ out)
{
  unsigned long long cnt = cnt_acc[0];
  if (cnt == 0ull) cnt = 1ull;
  const float f = (float)(loss_acc[0] / (double)cnt);
  const unsigned u = __float_as_uint(f);
  const unsigned bf = (u + 0x7FFFu + ((u >> 16) & 1u)) >> 16;
  out[0] = (u & 0xFFFF0000u) | (bf & 0xFFFFu);
}

extern "C" void kernel_launch(void* const* d_in, const int* in_sizes, int n_in,
                              void* d_out, int out_size, void* d_ws, size_t ws_size,
                              hipStream_t stream)
{
  const int* src_seq = (const int*)d_in[0];
  const int* tgt_seq = (const int*)d_in[1];
  const float* enc_emb = (const float*)d_in[2];
  const float* enc_Wih = (const float*)d_in[3];
  const float* enc_Whh = (const float*)d_in[4];
  const float* enc_bih = (const float*)d_in[5];
  const float* enc_bhh = (const float*)d_in[6];
  const float* dec_emb = (const float*)d_in[7];
  const float* dec_Wih = (const float*)d_in[8];
  const float* dec_Whh = (const float*)d_in[9];
  const float* dec_bih = (const float*)d_in[10];
  const float* dec_bhh = (const float*)d_in[11];
  const float* unemb_W = (const float*)d_in[12];
  const float* unemb_b = (const float*)d_in[13];

  // ---- workspace carve-up (~64 MB) ----
  char* p = (char*)d_ws;
  ushort_t* hseq = (ushort_t*)p; p += (size_t)NSLOT * Bn * Hn * 2;   // 36 MB ring
  ushort_t* eWih = (ushort_t*)p; p += (size_t)3 * Hn * En * 2;
  ushort_t* eWhh = (ushort_t*)p; p += (size_t)3 * Hn * Hn * 2;
  ushort_t* dWih = (ushort_t*)p; p += (size_t)3 * Hn * En * 2;
  ushort_t* dWhh = (ushort_t*)p; p += (size_t)3 * Hn * Hn * 2;
  ushort_t* eEmb = (ushort_t*)p; p += (size_t)256 * En * 2;
  ushort_t* dEmb = (ushort_t*)p; p += (size_t)256 * En * 2;
  ushort_t* Wp   = (ushort_t*)p; p += (size_t)256 * Hn * 2;
  float* Pe = (float*)p; p += (size_t)256 * 3072 * 4;   // 3 MB
  float* Pd = (float*)p; p += (size_t)256 * 3072 * 4;   // 3 MB
  double* loss_acc = (double*)p;
  unsigned long long* cnt_acc = (unsigned long long*)(p + 8);

  ushort_t* slot7 = hseq + (size_t)7 * Bn * Hn;
  ushort_t* slot8 = hseq + (size_t)8 * Bn * Hn;

  hipMemsetAsync(slot7, 0, (size_t)Bn * Hn * 2, stream);
  hipMemsetAsync(loss_acc, 0, 16, stream);

  // ---- fp32 -> bf16 conversions ----
  struct { const float* src; ushort_t* dst; int n; } cv[6] = {
      {enc_Wih, eWih, 3 * Hn * En}, {enc_Whh, eWhh, 3 * Hn * Hn},
      {dec_Wih, dWih, 3 * Hn * En}, {dec_Whh, dWhh, 3 * Hn * Hn},
      {enc_emb, eEmb, 256 * En},    {dec_emb, dEmb, 256 * En}};
  for (int i = 0; i < 6; ++i) {
    int n4 = cv[i].n / 4;
    cvt_bf16_kernel<<<(n4 + 255) / 256, 256, 0, stream>>>(cv[i].src, cv[i].dst, n4);
  }
  cvt_pad_wu_kernel<<<(256 * Hn / 4 + 255) / 256, 256, 0, stream>>>(unemb_W, Wp);

  // ---- xp tables: P = emb @ Wih^T + bih ----
  {
    const dim3 pg(4, 48);
    pgemm_kernel<<<pg, 256, 0, stream>>>(eEmb, eWih, enc_bih, Pe);
    pgemm_kernel<<<pg, 256, 0, stream>>>(dEmb, dWih, dec_bih, Pd);
  }

  // ---- encoder: 64 steps, ping-pong slots 7/8 (bf16 h only) ----
  const ushort_t* in_b = slot7;
  for (int s = 0; s < 64; ++s) {
    ushort_t* out_b = (s & 1) ? slot7 : slot8;
    gru_step_mfma<<<512, 512, 0, stream>>>(src_seq + (size_t)s * Bn, Pe, eWhh, enc_bhh,
                                           in_b, out_b);
    in_b = out_b;
  }
  // encoder final: slot7 (s=63 odd)

  // ---- decoder: 47 steps; h_b history ring; batched unembed every 8 ----
  int done = 0;
  for (int s = 0; s < 47; ++s) {
    const ushort_t* din_b = (s == 0) ? slot7 : hseq + (size_t)((s - 1) % NSLOT) * Bn * Hn;
    ushort_t* dout_b = hseq + (size_t)(s % NSLOT) * Bn * Hn;
    gru_step_mfma<<<512, 512, 0, stream>>>(tgt_seq + (size_t)s * Bn, Pd, dWhh, dec_bhh,
                                           din_b, dout_b);
    if (s == 7 || s == 15 || s == 23 || s == 31 || s == 39 || s == 46) {
      const int cnt = s + 1 - done;
      unembed_batched<<<cnt * 32, 256, 0, stream>>>(hseq, done, Wp, unemb_b, tgt_seq,
                                                    loss_acc, cnt_acc);
      done = s + 1;
    }
  }

  finalize_kernel<<<1, 1, 0, stream>>>(loss_acc, cnt_acc, (unsigned*)d_out);
}

// Round 20
// 2473.952 us; speedup vs baseline: 1.2734x; 1.0038x over previous
//
#include <hip/hip_runtime.h>
#include <math.h>

typedef unsigned short ushort_t;
typedef __attribute__((ext_vector_type(8))) short short8;   // 8 bf16 (4 VGPRs)
typedef __attribute__((ext_vector_type(4))) float f32x4;    // MFMA C/D

#define Bn 2048
#define Hn 1024
#define En 512
#define NSLOT 9

__device__ __forceinline__ float sigmoidf_(float x) { return 1.f / (1.f + expf(-x)); }

__device__ __forceinline__ ushort_t bf16rn(float f) {
  unsigned u = __float_as_uint(f);
  return (ushort_t)((u + 0x7FFFu + ((u >> 16) & 1u)) >> 16);
}

__device__ __forceinline__ float bf2f(ushort_t u) {
  return __uint_as_float(((unsigned)u) << 16);
}

__global__ __launch_bounds__(256) void cvt_bf16_kernel(const float* __restrict__ in,
                                                       ushort_t* __restrict__ out, int n4) {
  int i = blockIdx.x * 256 + threadIdx.x;
  if (i < n4) {
    float4 v = ((const float4*)in)[i];
    ushort4 o;
    o.x = bf16rn(v.x); o.y = bf16rn(v.y); o.z = bf16rn(v.z); o.w = bf16rn(v.w);
    ((ushort4*)out)[i] = o;
  }
}

// unemb_W [254][1024] f32 -> [256][1024] bf16, rows 254/255 = 0
__global__ __launch_bounds__(256) void cvt_pad_wu_kernel(const float* __restrict__ src,
                                                         ushort_t* __restrict__ dst) {
  int i = blockIdx.x * 256 + threadIdx.x;
  if (i < 256 * Hn / 4) {
    float4 v = make_float4(0.f, 0.f, 0.f, 0.f);
    if (i * 4 < 254 * Hn) v = ((const float4*)src)[i];
    ushort4 o;
    o.x = bf16rn(v.x); o.y = bf16rn(v.y); o.z = bf16rn(v.z); o.w = bf16rn(v.w);
    ((ushort4*)dst)[i] = o;
  }
}

#define GLOAD(gsrc, ldst)                                                      \
  __builtin_amdgcn_global_load_lds(                                            \
      (const __attribute__((address_space(1))) unsigned int*)(gsrc),           \
      (__attribute__((address_space(3))) unsigned int*)(ldst), 16, 0, 0)

// counted-vmcnt pipeline barrier: drain own loads to N, raw barrier, pin sched.
#define PIPE_BAR(N)                                                            \
  asm volatile("s_waitcnt vmcnt(" #N ")" ::: "memory");                        \
  __builtin_amdgcn_s_barrier();                                                \
  __builtin_amdgcn_sched_barrier(0);

// bank swizzle for 64 B rows (4 chunks): chunk' = chunk ^ ((row>>1)&3)
#define SWZ(ROW, C) ((C) ^ (((ROW) >> 1) & 3))
// bank swizzle for 128 B rows (8 chunks): chunk' = chunk ^ (row&7)
#define SWZ64(ROW, C) ((C) ^ ((ROW) & 7))

// ---------------------------------------------------------------------------
// xp table: P[v][g] = sum_e emb[v][e]*Wih[g][e] + bih[g]   (v<256, g<3072)
// ---------------------------------------------------------------------------
__global__ __launch_bounds__(256) void pgemm_kernel(
    const ushort_t* __restrict__ A,    // [256][512] bf16 (emb)
    const ushort_t* __restrict__ Bw,   // [3072][512] bf16 (Wih)
    const float* __restrict__ bias,    // [3072] (bih)
    float* __restrict__ P)             // [256][3072] f32
{
  __shared__ __align__(16) ushort_t As[64 * 32];
  __shared__ __align__(16) ushort_t Bs[64 * 32];

  const int tid = threadIdx.x;
  const int lane = tid & 63;
  const int wid = tid >> 6;
  const int wr = wid >> 1, wc = wid & 1;
  const int m0 = blockIdx.x * 64;
  const int n0 = blockIdx.y * 64;

  const int srow = tid >> 2;
  const int sseg = SWZ(srow, tid & 3) * 8;
  const ushort_t* aP = A + (size_t)(m0 + srow) * En + sseg;
  const ushort_t* bP = Bw + (size_t)(n0 + srow) * En + sseg;

  const int kc = lane >> 4;
  const int ra0 = wr * 32 + (lane & 15), ra1 = ra0 + 16;
  const int rb0 = wc * 32 + (lane & 15), rb1 = rb0 + 16;
  const int aoff0 = ra0 * 32 + SWZ(ra0, kc) * 8;
  const int aoff1 = ra1 * 32 + SWZ(ra1, kc) * 8;
  const int boff0 = rb0 * 32 + SWZ(rb0, kc) * 8;
  const int boff1 = rb1 * 32 + SWZ(rb1, kc) * 8;

  const f32x4 zero = {0.f, 0.f, 0.f, 0.f};
  f32x4 acc[2][2] = {{zero, zero}, {zero, zero}};

  for (int k0 = 0; k0 < En; k0 += 32) {
    GLOAD(aP + k0, &As[wid * 512]);
    GLOAD(bP + k0, &Bs[wid * 512]);
    asm volatile("s_waitcnt vmcnt(0)" ::: "memory");
    __syncthreads();
    short8 a0 = *(const short8*)&As[aoff0];
    short8 a1 = *(const short8*)&As[aoff1];
    short8 b0 = *(const short8*)&Bs[boff0];
    short8 b1 = *(const short8*)&Bs[boff1];
    acc[0][0] = __builtin_amdgcn_mfma_f32_16x16x32_bf16(a0, b0, acc[0][0], 0, 0, 0);
    acc[0][1] = __builtin_amdgcn_mfma_f32_16x16x32_bf16(a0, b1, acc[0][1], 0, 0, 0);
    acc[1][0] = __builtin_amdgcn_mfma_f32_16x16x32_bf16(a1, b0, acc[1][0], 0, 0, 0);
    acc[1][1] = __builtin_amdgcn_mfma_f32_16x16x32_bf16(a1, b1, acc[1][1], 0, 0, 0);
    __syncthreads();
  }

  const int colb = n0 + wc * 32 + (lane & 15);
  const int rowb = m0 + wr * 32 + ((lane >> 4) << 2);
#pragma unroll
  for (int j = 0; j < 2; ++j) {
    const int g = colb + j * 16;
    const float bv = bias[g];
#pragma unroll
    for (int i = 0; i < 2; ++i)
#pragma unroll
      for (int reg = 0; reg < 4; ++reg)
        P[(size_t)(rowb + i * 16 + reg) * 3072 + g] = acc[i][j][reg] + bv;
  }
}

// ---------------------------------------------------------------------------
// GRU step v6 (R13/R19 known-good): tile 64(batch) x 64(h-col) x 3 gates,
// 512 threads (8 waves), 512 blocks => 2 blocks/CU, 16 waves/CU.
// BK=64, 16 K-iters, 2 LDS buffers, 2-phase counted pipeline.
// ---------------------------------------------------------------------------
#define KSTEP(BUF)                                                             \
  {                                                                            \
    short8 aF[2][2], bF[3][2];                                                 \
    _Pragma("unroll") for (int fi = 0; fi < 2; ++fi)                           \
        _Pragma("unroll") for (int h = 0; h < 2; ++h)                          \
            aF[fi][h] = *(const short8*)&As[BUF][aoff[fi][h]];                 \
    _Pragma("unroll") for (int g = 0; g < 3; ++g)                              \
        _Pragma("unroll") for (int h = 0; h < 2; ++h)                          \
            bF[g][h] = *(const short8*)&Bs[BUF][g][boff[h]];                   \
    __builtin_amdgcn_s_setprio(1);                                             \
    _Pragma("unroll") for (int h = 0; h < 2; ++h)                              \
        _Pragma("unroll") for (int g = 0; g < 3; ++g)                          \
            _Pragma("unroll") for (int fi = 0; fi < 2; ++fi)                   \
                acc[g][fi] = __builtin_amdgcn_mfma_f32_16x16x32_bf16(          \
                    aF[fi][h], bF[g][h], acc[g][fi], 0, 0, 0);                 \
    __builtin_amdgcn_s_setprio(0);                                             \
  }

#define GSTAGE(BUF, T)                                                         \
  {                                                                            \
    const int k0_ = (T) * 64;                                                  \
    GLOAD(aSrc + k0_, &As[BUF][wid * 512]);                                    \
    GLOAD(bSrc0 + k0_, &Bs[BUF][0][wid * 512]);                                \
    GLOAD(bSrc1 + k0_, &Bs[BUF][1][wid * 512]);                                \
    GLOAD(bSrc2 + k0_, &Bs[BUF][2][wid * 512]);                                \
  }

__global__ __launch_bounds__(512, 4) void gru_step_mfma(
    const int* __restrict__ seq_row,
    const float* __restrict__ P,          // [256][3072] f32 (xp + bih)
    const ushort_t* __restrict__ Whh,     // [3H][H] bf16
    const float* __restrict__ bhh,        // [3H]
    const ushort_t* __restrict__ h_in_b,  // [B][H] bf16
    ushort_t* __restrict__ h_out_b)       // [B][H] bf16
{
  __shared__ __align__(16) ushort_t As[2][64 * 64];      // 2 x 8 KB
  __shared__ __align__(16) ushort_t Bs[2][3][64 * 64];   // 2 x 24 KB
  __shared__ int toks[64];

  const int tid = threadIdx.x;
  const int lane = tid & 63;
  const int wid = tid >> 6;     // 0..7
  const int wr = wid & 1;       // 32-row band
  const int wc = wid >> 1;      // 16-col band (0..3)

  // XCD-affine swizzle: XCD q owns n-tiles {2q, 2q+1}. 512 blocks = 2/CU.
  const int bid = blockIdx.x;
  const int q = bid & 7, t_ = bid >> 3;          // t_ in 0..63
  const int n0 = ((q << 1) | (t_ & 1)) * 64;
  const int m0 = (t_ >> 1) * 64;                 // 32 m-tiles

  if (tid < 64) toks[tid] = seq_row[m0 + tid];
  __syncthreads();

  const int srow = tid >> 3;                     // 0..63
  const int sseg = SWZ64(srow, tid & 7) * 8;     // ushort offset in 64-elem row

  const ushort_t* aSrc  = h_in_b + (size_t)(m0 + srow) * Hn + sseg;
  const ushort_t* bSrc0 = Whh + (size_t)(0 * Hn + n0 + srow) * Hn + sseg;
  const ushort_t* bSrc1 = Whh + (size_t)(1 * Hn + n0 + srow) * Hn + sseg;
  const ushort_t* bSrc2 = Whh + (size_t)(2 * Hn + n0 + srow) * Hn + sseg;

  const int kc = lane >> 4;
  int aoff[2][2], boff[2];
#pragma unroll
  for (int fi = 0; fi < 2; ++fi) {
    const int ra = wr * 32 + fi * 16 + (lane & 15);
#pragma unroll
    for (int h = 0; h < 2; ++h) aoff[fi][h] = ra * 64 + SWZ64(ra, h * 4 + kc) * 8;
  }
  {
    const int rb = wc * 16 + (lane & 15);
#pragma unroll
    for (int h = 0; h < 2; ++h) boff[h] = rb * 64 + SWZ64(rb, h * 4 + kc) * 8;
  }

  const f32x4 zero = {0.f, 0.f, 0.f, 0.f};
  f32x4 acc[3][2];
#pragma unroll
  for (int g = 0; g < 3; ++g)
#pragma unroll
    for (int fi = 0; fi < 2; ++fi) acc[g][fi] = zero;

  // ---- 2-phase counted K-loop: 16 BK=64 steps over K=1024 ----
  GSTAGE(0, 0);
  int buf = 0;
  for (int t = 0; t < 15; ++t) {
    GSTAGE(buf ^ 1, t + 1);   // next stage in flight across the barrier
    PIPE_BAR(4)               // drain stage t only
    KSTEP(buf)
    buf ^= 1;
  }
  PIPE_BAR(0)                 // t=15
  KSTEP(buf)

  // ---- epilogue: xp gather from P + gates + state update (bf16 h only) ----
  const int n = n0 + wc * 16 + (lane & 15);
  const int rowl = wr * 32 + ((lane >> 4) << 2);   // local row base
  const float bhr = bhh[n];
  const float bhz = bhh[Hn + n];
  const float bhn = bhh[2 * Hn + n];
#pragma unroll
  for (int fi = 0; fi < 2; ++fi) {
#pragma unroll
    for (int reg = 0; reg < 4; ++reg) {
      const int lr = rowl + fi * 16 + reg;
      const int m = m0 + lr;
      const float* prow = P + (size_t)toks[lr] * 3072;
      const float xr = prow[n];
      const float xz = prow[Hn + n];
      const float xn = prow[2 * Hn + n];
      const float r = sigmoidf_(xr + acc[0][fi][reg] + bhr);
      const float z = sigmoidf_(xz + acc[1][fi][reg] + bhz);
      const float nn = tanhf(xn + r * (acc[2][fi][reg] + bhn));
      const float hv = bf2f(h_in_b[(size_t)m * Hn + n]);  // L2-hot re-read
      const float o = (1.f - z) * nn + z * hv;
      h_out_b[(size_t)m * Hn + n] = bf16rn(o);
    }
  }
}

// ---------------------------------------------------------------------------
// Batched unembed v5: block = 64 rows x 256 cols, K=1024, BK=32, THREE
// staging buffers (60 KB -> 2 blocks/CU = 8 waves/CU) with 2 stages in
// flight across each KSTEP (vmcnt(5), issue-after-barrier: race-free since
// buf (t+2)%3 was last read in KSTEP(t-1) which precedes the barrier).
// Logits overlay in bf16 (32 KB, fits in staging region). 32 blocks/step.
// ---------------------------------------------------------------------------
#define USTAGE(BUF, T)                                                         \
  {                                                                            \
    const int k0_ = (T) * 32;                                                  \
    GLOAD(ha + k0_, AsU(BUF) + uwid * 512);                                    \
    GLOAD(w0 + k0_, BsU(BUF) + 0 * 2048 + uwid * 512);                         \
    GLOAD(w1 + k0_, BsU(BUF) + 1 * 2048 + uwid * 512);                         \
    GLOAD(w2 + k0_, BsU(BUF) + 2 * 2048 + uwid * 512);                         \
    GLOAD(w3 + k0_, BsU(BUF) + 3 * 2048 + uwid * 512);                         \
  }

#define UPIPE_BAR(N)                                                           \
  asm volatile("s_waitcnt vmcnt(" #N ")" ::: "memory");                        \
  __builtin_amdgcn_s_barrier();                                                \
  __builtin_amdgcn_sched_barrier(0);

#define UKSTEP(BUF)                                                            \
  {                                                                            \
    short8 a_[4], b_[4];                                                       \
    _Pragma("unroll") for (int fi = 0; fi < 4; ++fi)                           \
        a_[fi] = *(const short8*)(AsU(BUF) + uaoff[fi]);                       \
    _Pragma("unroll") for (int fj = 0; fj < 4; ++fj)                           \
        b_[fj] = *(const short8*)(BsU(BUF) + uboff[fj]);                       \
    _Pragma("unroll") for (int fi = 0; fi < 4; ++fi)                           \
        _Pragma("unroll") for (int fj = 0; fj < 4; ++fj)                       \
            acc[fi][fj] = __builtin_amdgcn_mfma_f32_16x16x32_bf16(             \
                a_[fi], b_[fj], acc[fi][fj], 0, 0, 0);                         \
  }

__global__ __launch_bounds__(256) void unembed_batched(
    const ushort_t* __restrict__ hseq,  // [NSLOT][B][H] bf16 ring
    int s0,
    const ushort_t* __restrict__ Wp,    // [256][H] bf16 (rows 254/255 = 0)
    const float* __restrict__ bu,       // [254]
    const int* __restrict__ tgt_seq,    // [S_tgt][B]
    double* __restrict__ loss_acc,
    unsigned long long* __restrict__ cnt_acc)
{
  // carve: A bufs 3 x 4 KB at [0,12K) | B bufs 3 x 16 KB at [12K,60K)
  __shared__ __align__(16) char usmem[60 * 1024];
#define AsU(BUF) ((ushort_t*)usmem + (BUF) * 2048)                // 3 x 4 KB
#define BsU(BUF) ((ushort_t*)(usmem + 12 * 1024) + (BUF) * 8192)  // 3 x 16 KB
  ushort_t* lg = (ushort_t*)usmem;  // [64][256] bf16 = 32 KB overlay

  const int tid = threadIdx.x;
  const int lane = tid & 63;
  const int uwid = tid >> 6;

  const int step = blockIdx.x >> 5;                 // 32 blocks per step
  const int slot = (s0 + step) % NSLOT;
  const int m0 = (blockIdx.x & 31) * 64;
  const ushort_t* h_b = hseq + (size_t)slot * Bn * Hn;
  const int* labels = tgt_seq + (size_t)(s0 + step + 1) * Bn;

  const int srow = tid >> 2;
  const int sseg = SWZ(srow, tid & 3) * 8;

  const ushort_t* ha = h_b + (size_t)(m0 + srow) * Hn + sseg;
  const ushort_t* w0 = Wp + (size_t)(0 * 64 + srow) * Hn + sseg;
  const ushort_t* w1 = Wp + (size_t)(1 * 64 + srow) * Hn + sseg;
  const ushort_t* w2 = Wp + (size_t)(2 * 64 + srow) * Hn + sseg;
  const ushort_t* w3 = Wp + (size_t)(3 * 64 + srow) * Hn + sseg;

  const int kc = lane >> 4;
  int uaoff[4], uboff[4];
#pragma unroll
  for (int fi = 0; fi < 4; ++fi) {
    const int ra = fi * 16 + (lane & 15);
    uaoff[fi] = ra * 32 + SWZ(ra, kc) * 8;
  }
#pragma unroll
  for (int fj = 0; fj < 4; ++fj) {
    const int rb = uwid * 64 + fj * 16 + (lane & 15);
    uboff[fj] = rb * 32 + SWZ(rb, kc) * 8;
  }

  const f32x4 zero = {0.f, 0.f, 0.f, 0.f};
  f32x4 acc[4][4];
#pragma unroll
  for (int fi = 0; fi < 4; ++fi)
#pragma unroll
    for (int fj = 0; fj < 4; ++fj) acc[fi][fj] = zero;

  // ---- 3-buffer K-loop, 2 stages in flight: 32 BK=32 steps ----
  USTAGE(0, 0);
  USTAGE(1, 1);
  for (int t = 0; t < 30; ++t) {
    UPIPE_BAR(5)                     // drain stage t; stage t+1 stays in flight
    USTAGE((t + 2) % 3, t + 2);      // issue t+2 (overwrites buf read at t-1)
    UKSTEP(t % 3)
  }
  UPIPE_BAR(5)   // t=30
  UKSTEP(0)
  UPIPE_BAR(0)   // t=31
  UKSTEP(1)

  // ---- logits -> bf16 LDS overlay (bias + mask pad cols) ----
  __syncthreads();  // all ds_reads of staging done; safe to overwrite with lg
#pragma unroll
  for (int fj = 0; fj < 4; ++fj) {
    const int col = uwid * 64 + fj * 16 + (lane & 15);
    const float bv = (col < 254) ? bu[col] : 0.f;
#pragma unroll
    for (int fi = 0; fi < 4; ++fi) {
#pragma unroll
      for (int reg = 0; reg < 4; ++reg) {
        const int row = fi * 16 + (lane >> 4) * 4 + reg;
        lg[row * 256 + col] = bf16rn((col < 254) ? (acc[fi][fj][reg] + bv) : -1e30f);
      }
    }
  }
  __syncthreads();

  // ---- per-row log-softmax + NLL: wave w handles rows [w*16, w*16+16) ----
  float wsum = 0.f;
  int wcnt = 0;
#pragma unroll
  for (int rr = 0; rr < 16; ++rr) {
    const int r = uwid * 16 + rr;
    const ushort4 u4 = *(const ushort4*)&lg[r * 256 + lane * 4];
    const float v0 = bf2f(u4.x), v1 = bf2f(u4.y), v2 = bf2f(u4.z), v3 = bf2f(u4.w);
    float mx = fmaxf(fmaxf(v0, v1), fmaxf(v2, v3));
    for (int o = 32; o > 0; o >>= 1) mx = fmaxf(mx, __shfl_xor(mx, o));
    float s = expf(v0 - mx) + expf(v1 - mx) + expf(v2 - mx) + expf(v3 - mx);
    for (int o = 32; o > 0; o >>= 1) s += __shfl_xor(s, o);
    if (lane == 0) {
      const int lab = labels[m0 + r];
      if (lab != 0) {
        wsum += (logf(s) + mx) - bf2f(lg[r * 256 + lab - 2]);
        wcnt += 1;
      }
    }
  }
  if (lane == 0) {
    atomicAdd(loss_acc, (double)wsum);
    atomicAdd(cnt_acc, (unsigned long long)wcnt);
  }
}

__global__ void finalize_kernel(const double* __restrict__ loss_acc,
                                const unsigned long long* __restrict__ cnt_acc,
                                unsigned* __restrict__ out)
{
  unsigned long long cnt = cnt_acc[0];
  if (cnt == 0ull) cnt = 1ull;
  const float f = (float)(loss_acc[0] / (double)cnt);
  const unsigned u = __float_as_uint(f);
  const unsigned bf = (u + 0x7FFFu + ((u >> 16) & 1u)) >> 16;
  out[0] = (u & 0xFFFF0000u) | (bf & 0xFFFFu);
}

extern "C" void kernel_launch(void* const* d_in, const int* in_sizes, int n_in,
                              void* d_out, int out_size, void* d_ws, size_t ws_size,
                              hipStream_t stream)
{
  const int* src_seq = (const int*)d_in[0];
  const int* tgt_seq = (const int*)d_in[1];
  const float* enc_emb = (const float*)d_in[2];
  const float* enc_Wih = (const float*)d_in[3];
  const float* enc_Whh = (const float*)d_in[4];
  const float* enc_bih = (const float*)d_in[5];
  const float* enc_bhh = (const float*)d_in[6];
  const float* dec_emb = (const float*)d_in[7];
  const float* dec_Wih = (const float*)d_in[8];
  const float* dec_Whh = (const float*)d_in[9];
  const float* dec_bih = (const float*)d_in[10];
  const float* dec_bhh = (const float*)d_in[11];
  const float* unemb_W = (const float*)d_in[12];
  const float* unemb_b = (const float*)d_in[13];

  // ---- workspace carve-up (~64 MB) ----
  char* p = (char*)d_ws;
  ushort_t* hseq = (ushort_t*)p; p += (size_t)NSLOT * Bn * Hn * 2;   // 36 MB ring
  ushort_t* eWih = (ushort_t*)p; p += (size_t)3 * Hn * En * 2;
  ushort_t* eWhh = (ushort_t*)p; p += (size_t)3 * Hn * Hn * 2;
  ushort_t* dWih = (ushort_t*)p; p += (size_t)3 * Hn * En * 2;
  ushort_t* dWhh = (ushort_t*)p; p += (size_t)3 * Hn * Hn * 2;
  ushort_t* eEmb = (ushort_t*)p; p += (size_t)256 * En * 2;
  ushort_t* dEmb = (ushort_t*)p; p += (size_t)256 * En * 2;
  ushort_t* Wp   = (ushort_t*)p; p += (size_t)256 * Hn * 2;
  float* Pe = (float*)p; p += (size_t)256 * 3072 * 4;   // 3 MB
  float* Pd = (float*)p; p += (size_t)256 * 3072 * 4;   // 3 MB
  double* loss_acc = (double*)p;
  unsigned long long* cnt_acc = (unsigned long long*)(p + 8);

  ushort_t* slot7 = hseq + (size_t)7 * Bn * Hn;
  ushort_t* slot8 = hseq + (size_t)8 * Bn * Hn;

  hipMemsetAsync(slot7, 0, (size_t)Bn * Hn * 2, stream);
  hipMemsetAsync(loss_acc, 0, 16, stream);

  // ---- fp32 -> bf16 conversions ----
  struct { const float* src; ushort_t* dst; int n; } cv[6] = {
      {enc_Wih, eWih, 3 * Hn * En}, {enc_Whh, eWhh, 3 * Hn * Hn},
      {dec_Wih, dWih, 3 * Hn * En}, {dec_Whh, dWhh, 3 * Hn * Hn},
      {enc_emb, eEmb, 256 * En},    {dec_emb, dEmb, 256 * En}};
  for (int i = 0; i < 6; ++i) {
    int n4 = cv[i].n / 4;
    cvt_bf16_kernel<<<(n4 + 255) / 256, 256, 0, stream>>>(cv[i].src, cv[i].dst, n4);
  }
  cvt_pad_wu_kernel<<<(256 * Hn / 4 + 255) / 256, 256, 0, stream>>>(unemb_W, Wp);

  // ---- xp tables: P = emb @ Wih^T + bih ----
  {
    const dim3 pg(4, 48);
    pgemm_kernel<<<pg, 256, 0, stream>>>(eEmb, eWih, enc_bih, Pe);
    pgemm_kernel<<<pg, 256, 0, stream>>>(dEmb, dWih, dec_bih, Pd);
  }

  // ---- encoder: 64 steps, ping-pong slots 7/8 (bf16 h only) ----
  const ushort_t* in_b = slot7;
  for (int s = 0; s < 64; ++s) {
    ushort_t* out_b = (s & 1) ? slot7 : slot8;
    gru_step_mfma<<<512, 512, 0, stream>>>(src_seq + (size_t)s * Bn, Pe, eWhh, enc_bhh,
                                           in_b, out_b);
    in_b = out_b;
  }
  // encoder final: slot7 (s=63 odd)

  // ---- decoder: 47 steps; h_b history ring; batched unembed every 8 ----
  int done = 0;
  for (int s = 0; s < 47; ++s) {
    const ushort_t* din_b = (s == 0) ? slot7 : hseq + (size_t)((s - 1) % NSLOT) * Bn * Hn;
    ushort_t* dout_b = hseq + (size_t)(s % NSLOT) * Bn * Hn;
    gru_step_mfma<<<512, 512, 0, stream>>>(tgt_seq + (size_t)s * Bn, Pd, dWhh, dec_bhh,
                                           din_b, dout_b);
    if (s == 7 || s == 15 || s == 23 || s == 31 || s == 39 || s == 46) {
      const int cnt = s + 1 - done;
      unembed_batched<<<cnt * 32, 256, 0, stream>>>(hseq, done, Wp, unemb_b, tgt_seq,
                                                    loss_acc, cnt_acc);
      done = s + 1;
    }
  }

  finalize_kernel<<<1, 1, 0, stream>>>(loss_acc, cnt_acc, (unsigned*)d_out);
}